// Round 6
// baseline (3255.006 us; speedup 1.0000x reference)
//
#include <hip/hip_runtime.h>
#include <hip/hip_bf16.h>

// B=1024, L=128, W=512, S=8, STEPS=12, VOCAB=32, NLAB=10

typedef unsigned short u16;
typedef __attribute__((ext_vector_type(8))) short short8;   // 8 x bf16
typedef __attribute__((ext_vector_type(4))) float f32x4;

__device__ __forceinline__ float bf2f(u16 v) {
    union { unsigned int u; float f; } x; x.u = ((unsigned int)v) << 16; return x.f;
}
__device__ __forceinline__ u16 f2bf(float f) {
    union { float f; unsigned int u; } x; x.f = f;
    unsigned int u = x.u;
    return (u16)((u + 0x7FFFu + ((u >> 16) & 1u)) >> 16);   // RNE
}
__device__ __forceinline__ float sigmoidf_(float v) { return 1.f / (1.f + expf(-v)); }

union U4 { ushort4 v; u16 e[4]; };

// ---------------------------------------------------------------------------
// Input-dtype detection (bf16 vs f32 inputs) — same as R5 (f32 confirmed, but
// keep robust).
// ---------------------------------------------------------------------------
__device__ __forceinline__ int sane16(u16 u) {
    if ((u & 0x7FFF) == 0) return 1;
    int e = (u >> 7) & 0xFF;
    return (e >= 0x33 && e <= 0x43) ? 1 : 0;
}
__global__ __launch_bounds__(256) void detect_k(const u16* __restrict__ raw,
                                                int* __restrict__ flag) {
    const int t = threadIdx.x;
    int c = sane16(raw[1024 + t * 2]) + sane16(raw[1024 + t * 2 + 1]);
#pragma unroll
    for (int off = 32; off; off >>= 1) c += __shfl_down(c, off, 64);
    __shared__ int red[4];
    if ((t & 63) == 0) red[t >> 6] = c;
    __syncthreads();
    if (t == 0) *flag = (red[0] + red[1] + red[2] + red[3] >= 448) ? 1 : 0;
}

// ---------------------------------------------------------------------------
// Canonicalize float tensors to bf16, vectorized (float4 in, ushort4 out).
// ---------------------------------------------------------------------------
struct CT { const void* src[20]; int n[20]; int off[20]; };
__global__ __launch_bounds__(256) void conv_k(CT ct, u16* __restrict__ dstBase,
                                              const int* __restrict__ flag) {
    const int isbf = *flag;
    const int gid = blockIdx.x * 256 + threadIdx.x;
    const int stride = gridDim.x * 256;
    for (int tn = 0; tn < 20; ++tn) {
        const int n = ct.n[tn];
        const int n4 = n >> 2;
        u16* dst = dstBase + ct.off[tn];
        if (!isbf) {
            const float* s = (const float*)ct.src[tn];
            for (int i = gid; i < n4; i += stride) {
                f32x4 v = *(const f32x4*)(s + i * 4);
                ushort4 o = make_ushort4(f2bf(v[0]), f2bf(v[1]), f2bf(v[2]), f2bf(v[3]));
                *(ushort4*)(dst + i * 4) = o;
            }
            if (gid < (n & 3)) { int i = n4 * 4 + gid; dst[i] = f2bf(s[i]); }
        } else {
            const u16* s = (const u16*)ct.src[tn];
            for (int i = gid; i < n4; i += stride)
                *(ushort4*)(dst + i * 4) = *(const ushort4*)(s + i * 4);
            if (gid < (n & 3)) { int i = n4 * 4 + gid; dst[i] = s[i]; }
        }
    }
}

// ---------------------------------------------------------------------------
// Batched GEMM: C[z][m][n] = epi( sum_k A[z][m][k] * Bw[z][n][k] )
// 128x128 tile, BK=64, 4 waves, mfma_f32_16x16x32_bf16, XOR-swizzled LDS.
// Register-prefetch pipeline: tile k+1 loads issued after the staging barrier
// so they fly during the MFMA phase (raises memory-level parallelism).
// Grid: x = weightId (nTile + nt*z)  [XCD swizzle: 8 m-blocks sharing a
// weight tile land on one XCD], y = m-tile.
// ---------------------------------------------------------------------------
struct GP {
    const u16* A;  long lda; long aOff[16];
    const u16* Bw; long ldb; long bwOff[16];
    const u16* bias; long biasOff[16];
    const u16* add; long ldadd; long addOff;    // EPI 1/7
    const float* gate;                           // EPI 3
    void* C; long ldc; long cOff[16];
    float* C2;                                   // EPI 4: h f32
    u16* C3;                                     // EPI 4: summ_b
    int K; int nt;
};

template<int EPI>
__global__ __launch_bounds__(256) void gemm_k(GP p) {
    __shared__ __align__(16) u16 lA[128 * 64];
    __shared__ __align__(16) u16 lB[128 * 64];
    const int t    = threadIdx.x;
    const int lane = t & 63;
    const int wv   = t >> 6;
    const int bx   = blockIdx.x;
    const int z    = bx / p.nt;
    const int n0   = (bx - z * p.nt) * 128;
    const int m0   = blockIdx.y * 128;

    const u16* Ab = p.A + p.aOff[z] + (long)m0 * p.lda;
    const u16* Bb = p.Bw + p.bwOff[z] + (long)n0 * p.ldb;

    f32x4 acc[4][4];
#pragma unroll
    for (int i = 0; i < 4; i++)
#pragma unroll
        for (int j = 0; j < 4; j++) acc[i][j] = (f32x4){0.f, 0.f, 0.f, 0.f};

    const int wm   = (wv & 1) * 64;
    const int wn   = (wv >> 1) * 64;
    const int fr   = lane & 15;
    const int quad = lane >> 4;

    // LDS[row][c8] = Global[row][c8 ^ (row&7)]  (XOR bank swizzle)
    int rowA[4], src8A[4];
#pragma unroll
    for (int it = 0; it < 4; ++it) {
        int flat = it * 256 + t;
        rowA[it] = flat >> 3;
        src8A[it] = (flat & 7) ^ (rowA[it] & 7);
    }

    const int nk = p.K >> 6;
    short8 ra[4], rb[4];
#pragma unroll
    for (int it = 0; it < 4; ++it)
        ra[it] = *(const short8*)(Ab + (long)rowA[it] * p.lda + src8A[it] * 8);
#pragma unroll
    for (int it = 0; it < 4; ++it)
        rb[it] = *(const short8*)(Bb + (long)rowA[it] * p.ldb + src8A[it] * 8);

    for (int kt = 0; kt < nk; ++kt) {
#pragma unroll
        for (int it = 0; it < 4; ++it) {
            int flat = it * 256 + t;
            *(short8*)&lA[flat * 8] = ra[it];
            *(short8*)&lB[flat * 8] = rb[it];
        }
        __syncthreads();
        if (kt + 1 < nk) {                       // prefetch next tile -> regs
            const long kb = (long)(kt + 1) * 64;
#pragma unroll
            for (int it = 0; it < 4; ++it)
                ra[it] = *(const short8*)(Ab + (long)rowA[it] * p.lda + kb + src8A[it] * 8);
#pragma unroll
            for (int it = 0; it < 4; ++it)
                rb[it] = *(const short8*)(Bb + (long)rowA[it] * p.ldb + kb + src8A[it] * 8);
        }
#pragma unroll
        for (int kk = 0; kk < 2; ++kk) {
            const int q = kk * 4 + quad;
            short8 aF[4], bF[4];
#pragma unroll
            for (int mi = 0; mi < 4; mi++) {
                int row = wm + mi * 16 + fr;
                aF[mi] = *(const short8*)&lA[row * 64 + (q ^ (row & 7)) * 8];
            }
#pragma unroll
            for (int ni = 0; ni < 4; ni++) {
                int row = wn + ni * 16 + fr;
                bF[ni] = *(const short8*)&lB[row * 64 + (q ^ (row & 7)) * 8];
            }
#pragma unroll
            for (int mi = 0; mi < 4; mi++)
#pragma unroll
                for (int ni = 0; ni < 4; ni++)
                    acc[mi][ni] = __builtin_amdgcn_mfma_f32_16x16x32_bf16(
                        aF[mi], bF[ni], acc[mi][ni], 0, 0, 0);
        }
        __syncthreads();
    }

    // Epilogue: D row = quad*4+reg, col = lane&15
#pragma unroll
    for (int mi = 0; mi < 4; mi++) {
#pragma unroll
        for (int ni = 0; ni < 4; ni++) {
            const int mg = m0 + wm + mi * 16 + quad * 4;
            const int ng = n0 + wn + ni * 16 + fr;
#pragma unroll
            for (int r = 0; r < 4; r++) {
                float v = acc[mi][ni][r];
                const long row = mg + r;
                if (EPI == 1) {        // tanh(acc+add+bias) -> bf16   [link]
                    float ad = bf2f(p.add[z * p.addOff + row * p.ldadd + ng]);
                    v = tanhf(v + ad + bf2f(p.bias[p.biasOff[z] + ng]));
                    ((u16*)p.C)[p.cOff[z] + row * p.ldc + ng] = f2bf(v);
                } else if (EPI == 3) { // gate*tanh(acc+bias) -> bf16  [upd]
                    v = tanhf(v + bf2f(p.bias[p.biasOff[z] + ng]));
                    v *= p.gate[row * 8 + z];
                    ((u16*)p.C)[p.cOff[z] + row * p.ldc + ng] = f2bf(v);
                } else if (EPI == 4) { // encode mix: h_b, summ_b, h(f32)
                    v = tanhf(v + bf2f(p.bias[ng]));
                    u16 b = f2bf(v);
                    ((u16*)p.C)[row * 512 + ng] = b;
                    p.C3[row * 512 + ng] = b;
                    p.C2[row * 512 + ng] = v;
                } else if (EPI == 6) { // (acc+bias) -> bf16           [cin, gih]
                    v = v + bf2f(p.bias[p.biasOff[z] + ng]);
                    ((u16*)p.C)[p.cOff[z] + row * p.ldc + ng] = f2bf(v);
                } else {               // EPI 7: tanh(acc+add) -> bf16 [f0]
                    float ad = bf2f(p.add[row * p.ldadd + ng]);
                    v = tanhf(v + ad);
                    ((u16*)p.C)[row * p.ldc + ng] = f2bf(v);
                }
            }
        }
    }
}

// ---------------------------------------------------------------------------
// Encode: masked mean / masked max / last token -> cat [B,1536]
// ---------------------------------------------------------------------------
__global__ __launch_bounds__(256) void encode_k(const int* __restrict__ x,
                                                const u16* __restrict__ embed,
                                                u16* __restrict__ cat) {
    __shared__ int toks[128];
    __shared__ int cnt_s;
    const int b = blockIdx.x, t = threadIdx.x;
    if (t < 128) toks[t] = x[b * 128 + t];
    __syncthreads();
    if (t == 0) {
        int c = 0;
        for (int l = 0; l < 128; l++) c += (toks[l] != 0);
        cnt_s = c;
    }
    __syncthreads();
    const int cnt = cnt_s;
    const int lastTok = toks[cnt > 0 ? cnt - 1 : 0];
    for (int w = t; w < 512; w += 256) {
        float sum = 0.f, mx = -10000.f;
        for (int l = 0; l < 128; l++) {
            int tok = toks[l];
            if (tok != 0) {
                float e = bf2f(embed[tok * 512 + w]);
                sum += e;
                mx = fmaxf(mx, e);
            }
        }
        float mean = sum / (float)(cnt > 0 ? cnt : 1);
        float last = bf2f(embed[lastTok * 512 + w]);
        cat[(long)b * 1536 + w]        = f2bf(mean);
        cat[(long)b * 1536 + 512 + w]  = f2bf(mx);
        cat[(long)b * 1536 + 1024 + w] = f2bf(last);
    }
}

// ---------------------------------------------------------------------------
// Fused GRU + gate-dot + prismion. gih bf16 [B, 16*1536]: z<8 = gi slices,
// z>=8 = gh slices. One block per (b,s), 128 threads x 4 elems.
// ---------------------------------------------------------------------------
__global__ __launch_bounds__(128) void gru_k(const u16* __restrict__ gih,
                                             float* __restrict__ hs,
                                             u16* __restrict__ hs_b,
                                             u16* __restrict__ prism,
                                             float* __restrict__ gate,
                                             const u16* __restrict__ Wg,
                                             const u16* __restrict__ bg,
                                             const u16* __restrict__ phase,
                                             const u16* __restrict__ pgain) {
    const int bs = blockIdx.x;
    const int b = bs >> 3, s = bs & 7;
    const int t = threadIdx.x;
    const int w = t * 4;
    const long gbase = (long)b * 24576 + s * 1536;
    const long hbase = (long)b * 4096 + s * 512;

    U4 ir, iz, in_, hr, hz, hn;
    ir.v  = *(const ushort4*)(gih + gbase + w);
    iz.v  = *(const ushort4*)(gih + gbase + 512 + w);
    in_.v = *(const ushort4*)(gih + gbase + 1024 + w);
    hr.v  = *(const ushort4*)(gih + gbase + 12288 + w);
    hz.v  = *(const ushort4*)(gih + gbase + 12288 + 512 + w);
    hn.v  = *(const ushort4*)(gih + gbase + 12288 + 1024 + w);
    f32x4 h = *(const f32x4*)(hs + hbase + w);

    float gpart = 0.f;
    f32x4 hnew;
    u16 hb[4], pb[4];
#pragma unroll
    for (int i = 0; i < 4; i++) {
        float r  = sigmoidf_(bf2f(ir.e[i]) + bf2f(hr.e[i]));
        float zz = sigmoidf_(bf2f(iz.e[i]) + bf2f(hz.e[i]));
        float n  = tanhf(bf2f(in_.e[i]) + r * bf2f(hn.e[i]));
        float hv = (1.f - zz) * n + zz * h[i];
        hnew[i] = hv;
        hb[i] = f2bf(hv);
        gpart += bf2f(Wg[s * 512 + w + i]) * hv;
        float ph = bf2f(phase[s * 512 + w + i]);
        float pg = bf2f(pgain[s * 512 + w + i]);
        float gain = (pg > 20.f) ? pg : log1pf(expf(pg));
        float c = cosf(hv + ph);
        pb[i] = f2bf(c * c * gain);
    }
    *(f32x4*)(hs + hbase + w) = hnew;
    *(ushort4*)(hs_b + hbase + w)  = make_ushort4(hb[0], hb[1], hb[2], hb[3]);
    *(ushort4*)(prism + hbase + w) = make_ushort4(pb[0], pb[1], pb[2], pb[3]);

#pragma unroll
    for (int off = 32; off; off >>= 1) gpart += __shfl_down(gpart, off, 64);
    __shared__ float red[2];
    if ((t & 63) == 0) red[t >> 6] = gpart;
    __syncthreads();
    if (t == 0) gate[bs] = sigmoidf_(red[0] + red[1] + bf2f(bg[s]));
}

// ---------------------------------------------------------------------------
// delta = sum_s upd / sqrt(S);  h = tanh(h*decay + delta); h_b = bf16(h)
// ---------------------------------------------------------------------------
__global__ __launch_bounds__(256) void hupd_k(const u16* __restrict__ upd,
                                              float* __restrict__ h,
                                              u16* __restrict__ h_b,
                                              const u16* __restrict__ decay_p) {
    const int idx = blockIdx.x * 256 + threadIdx.x;   // over B*W
    const int b = idx >> 9, w = idx & 511;
    const long base = (long)b * 4096 + w;
    float dsum = 0.f;
#pragma unroll
    for (int s = 0; s < 8; s++) dsum += bf2f(upd[base + s * 512]);
    const float decay = sigmoidf_(bf2f(decay_p[0]));
    const float hv = tanhf(h[idx] * decay + dsum * 0.35355339059327373f);
    h[idx] = hv;
    h_b[idx] = f2bf(hv);
}

// ---------------------------------------------------------------------------
// Final head: one wave per b; output dtype follows detected input dtype.
// ---------------------------------------------------------------------------
__global__ __launch_bounds__(64) void out_k(const float* __restrict__ h,
                                            const u16* __restrict__ Wout,
                                            const u16* __restrict__ bout,
                                            void* __restrict__ out,
                                            const int* __restrict__ flag) {
    const int b = blockIdx.x, lane = threadIdx.x;
    const int isbf = *flag;
    for (int j = 0; j < 10; j++) {
        float p = 0.f;
#pragma unroll
        for (int k = 0; k < 8; k++) {
            int w = lane + k * 64;
            p += h[(long)b * 512 + w] * bf2f(Wout[j * 512 + w]);
        }
#pragma unroll
        for (int off = 32; off; off >>= 1) p += __shfl_down(p, off, 64);
        if (lane == 0) {
            float val = p + bf2f(bout[j]);
            if (isbf) ((u16*)out)[b * 10 + j] = f2bf(val);
            else      ((float*)out)[b * 10 + j] = val;
        }
    }
}

// ---------------------------------------------------------------------------
extern "C" void kernel_launch(void* const* d_in, const int* in_sizes, int n_in,
                              void* d_out, int out_size, void* d_ws, size_t ws_size,
                              hipStream_t stream) {
    (void)n_in; (void)out_size; (void)ws_size;
    const int* x = (const int*)d_in[0];

    char* pp = (char*)d_ws;
    auto carve = [&](size_t n) { char* r = pp; pp += (n + 255) & ~(size_t)255; return (void*)r; };

    // canonical bf16 parameter block (~44 MB)
    CT ct;
    size_t ctot = 0;
    for (int i = 0; i < 20; i++) {
        ct.src[i] = d_in[i + 1];
        ct.n[i]   = in_sizes[i + 1];
        ct.off[i] = (int)ctot;
        ctot += ((size_t)in_sizes[i + 1] + 15) & ~(size_t)15;
    }
    u16* canon = (u16*)carve(ctot * 2);
    const u16* embed  = canon + ct.off[0];
    const u16* W_mix  = canon + ct.off[1];
    const u16* b_mix  = canon + ct.off[2];
    const u16* W_in   = canon + ct.off[3];
    const u16* b_in   = canon + ct.off[4];
    const u16* W_link = canon + ct.off[5];
    const u16* b_link = canon + ct.off[6];
    const u16* W_ih   = canon + ct.off[7];
    const u16* b_ih   = canon + ct.off[8];
    const u16* W_hh   = canon + ct.off[9];
    const u16* b_hh   = canon + ct.off[10];
    const u16* W_gate = canon + ct.off[11];
    const u16* b_gate = canon + ct.off[12];
    const u16* phase  = canon + ct.off[13];
    const u16* pgain  = canon + ct.off[14];
    const u16* W_delta= canon + ct.off[15];
    const u16* b_delta= canon + ct.off[16];
    const u16* decayp = canon + ct.off[17];
    const u16* W_out  = canon + ct.off[18];
    const u16* b_out  = canon + ct.off[19];

    int*   flag   = (int*)  carve(256);
    u16*   cat    = (u16*)  carve((size_t)1024 * 1536 * 2);    //  3 MB
    u16*   h_b    = (u16*)  carve((size_t)1024 * 512 * 2);     //  1 MB
    u16*   summ_b = (u16*)  carve((size_t)1024 * 512 * 2);     //  1 MB
    float* h      = (float*)carve((size_t)1024 * 512 * 4);     //  2 MB
    u16*   cin    = (u16*)  carve((size_t)1024 * 4096 * 2);    //  8 MB
    u16*   f0     = (u16*)  carve((size_t)1024 * 4096 * 2);    //  8 MB
    u16*   feats  = (u16*)  carve((size_t)1024 * 4096 * 2);    //  8 MB
    float* hs     = (float*)carve((size_t)1024 * 4096 * 4);    // 16 MB
    u16*   hs_b   = (u16*)  carve((size_t)1024 * 4096 * 2);    //  8 MB
    u16*   gih    = (u16*)  carve((size_t)1024 * 24576 * 2);   // 50 MB
    u16*   prism  = (u16*)  carve((size_t)1024 * 4096 * 2);    //  8 MB
    u16*   upd    = (u16*)  carve((size_t)1024 * 4096 * 2);    //  8 MB
    float* gate   = (float*)carve((size_t)1024 * 8 * 4);       // 32 KB

    (void)hipMemsetAsync(hs,   0, (size_t)1024 * 4096 * 4, stream);
    (void)hipMemsetAsync(hs_b, 0, (size_t)1024 * 4096 * 2, stream);

    detect_k<<<dim3(1), dim3(256), 0, stream>>>((const u16*)d_in[1], flag);
    conv_k<<<dim3(1024), dim3(256), 0, stream>>>(ct, canon, flag);
    encode_k<<<dim3(1024), dim3(256), 0, stream>>>(x, embed, cat);

    {   // summary = tanh(cat @ W_mix^T + b_mix) -> h_b, summ_b, h
        GP p{}; p.A = cat; p.lda = 1536; p.Bw = W_mix; p.ldb = 1536;
        p.bias = b_mix; p.C = h_b; p.ldc = 512; p.C2 = h; p.C3 = summ_b;
        p.K = 1536; p.nt = 4;
        gemm_k<4><<<dim3(4, 8, 1), dim3(256), 0, stream>>>(p);
    }
    {   // cin = summary @ W_in[:, :, 512:]^T + b_in   (loop-invariant half)
        GP p{}; p.A = summ_b; p.lda = 512; p.Bw = W_in + 512; p.ldb = 1024;
        p.bias = b_in; p.C = cin; p.ldc = 4096; p.K = 512; p.nt = 32;
        gemm_k<6><<<dim3(32, 8, 1), dim3(256), 0, stream>>>(p);
    }

    for (int step = 0; step < 12; ++step) {
        {   // f0 = tanh(h @ W_in[:, :, :512]^T + cin)
            GP p{}; p.A = h_b; p.lda = 512; p.Bw = W_in; p.ldb = 1024;
            p.add = cin; p.ldadd = 4096; p.C = f0; p.ldc = 4096;
            p.K = 512; p.nt = 32;
            gemm_k<7><<<dim3(32, 8, 1), dim3(256), 0, stream>>>(p);
        }
        {   // feats = tanh(f0 + prev @ W_link^T + b_link)
            GP p{}; p.A = f0; p.lda = 4096;
            for (int s = 0; s < 8; s++) p.aOff[s] = (long)((s + 7) & 7) * 512;
            p.Bw = W_link; p.ldb = 512;
            for (int s = 0; s < 8; s++) p.bwOff[s] = (long)s * 512 * 512;
            p.bias = b_link;
            for (int s = 0; s < 8; s++) p.biasOff[s] = (long)s * 512;
            p.add = f0; p.ldadd = 4096; p.addOff = 512;
            p.C = feats; p.ldc = 4096;
            for (int s = 0; s < 8; s++) p.cOff[s] = (long)s * 512;
            p.K = 512; p.nt = 4;
            gemm_k<1><<<dim3(32, 8, 1), dim3(256), 0, stream>>>(p);
        }
        {   // gih: z<8 -> gi = feats@W_ih^T+b_ih ; z>=8 -> gh = hs@W_hh^T+b_hh
            GP p{}; p.A = feats; p.lda = 4096;
            p.Bw = W_ih; p.ldb = 512;
            p.bias = b_ih;
            p.C = gih; p.ldc = 24576;
            for (int zz = 0; zz < 16; zz++) {
                if (zz < 8) {
                    p.aOff[zz]  = (long)zz * 512;
                    p.bwOff[zz] = (long)zz * 1536 * 512;
                    p.biasOff[zz] = (long)zz * 1536;
                } else {
                    p.aOff[zz]  = (long)(hs_b - feats) + (long)(zz - 8) * 512;
                    p.bwOff[zz] = (long)(W_hh - W_ih) + (long)(zz - 8) * 1536 * 512;
                    p.biasOff[zz] = (long)(b_hh - b_ih) + (long)(zz - 8) * 1536;
                }
                p.cOff[zz] = (long)zz * 1536;
            }
            p.K = 512; p.nt = 12;
            gemm_k<6><<<dim3(192, 8, 1), dim3(256), 0, stream>>>(p);
        }
        gru_k<<<dim3(8192), dim3(128), 0, stream>>>(gih, hs, hs_b, prism, gate,
                                                    W_gate, b_gate, phase, pgain);
        {   // upd = gate * tanh(prism @ W_delta^T + b_delta) -> bf16
            GP p{}; p.A = prism; p.lda = 4096;
            for (int s = 0; s < 8; s++) p.aOff[s] = (long)s * 512;
            p.Bw = W_delta; p.ldb = 512;
            for (int s = 0; s < 8; s++) p.bwOff[s] = (long)s * 512 * 512;
            p.bias = b_delta;
            for (int s = 0; s < 8; s++) p.biasOff[s] = (long)s * 512;
            p.gate = gate;
            p.C = upd; p.ldc = 4096;
            for (int s = 0; s < 8; s++) p.cOff[s] = (long)s * 512;
            p.K = 512; p.nt = 4;
            gemm_k<3><<<dim3(32, 8, 1), dim3(256), 0, stream>>>(p);
        }
        hupd_k<<<dim3(2048), dim3(256), 0, stream>>>(upd, h, h_b, decayp);
    }

    out_k<<<dim3(1024), dim3(64), 0, stream>>>(h, W_out, b_out, d_out, flag);
}

// Round 7
// 2569.323 us; speedup vs baseline: 1.2669x; 1.2669x over previous
//
#include <hip/hip_runtime.h>
#include <hip/hip_bf16.h>

// B=1024, L=128, W=512, S=8, STEPS=12, VOCAB=32, NLAB=10

typedef unsigned short u16;
typedef __attribute__((ext_vector_type(8))) short short8;   // 8 x bf16
typedef __attribute__((ext_vector_type(4))) float f32x4;

__device__ __forceinline__ float bf2f(u16 v) {
    union { unsigned int u; float f; } x; x.u = ((unsigned int)v) << 16; return x.f;
}
__device__ __forceinline__ u16 f2bf(float f) {
    union { float f; unsigned int u; } x; x.f = f;
    unsigned int u = x.u;
    return (u16)((u + 0x7FFFu + ((u >> 16) & 1u)) >> 16);   // RNE
}
__device__ __forceinline__ float sigmoidf_(float v) { return 1.f / (1.f + expf(-v)); }

union U4 { ushort4 v; u16 e[4]; };

// Async global->LDS, 16B/lane. LDS dest = wave-uniform base + lane*16 (our
// flat = it*256 + wv*64 + lane satisfies this). C-style casts = addrspacecast.
__device__ __forceinline__ void gload_lds16(const u16* g, u16* l) {
    __builtin_amdgcn_global_load_lds(
        (const __attribute__((address_space(1))) unsigned int*)g,
        (__attribute__((address_space(3))) unsigned int*)l, 16, 0, 0);
}

// ---------------------------------------------------------------------------
// Input-dtype detection (bf16 vs f32 inputs).
// ---------------------------------------------------------------------------
__device__ __forceinline__ int sane16(u16 u) {
    if ((u & 0x7FFF) == 0) return 1;
    int e = (u >> 7) & 0xFF;
    return (e >= 0x33 && e <= 0x43) ? 1 : 0;
}
__global__ __launch_bounds__(256) void detect_k(const u16* __restrict__ raw,
                                                int* __restrict__ flag) {
    const int t = threadIdx.x;
    int c = sane16(raw[1024 + t * 2]) + sane16(raw[1024 + t * 2 + 1]);
#pragma unroll
    for (int off = 32; off; off >>= 1) c += __shfl_down(c, off, 64);
    __shared__ int red[4];
    if ((t & 63) == 0) red[t >> 6] = c;
    __syncthreads();
    if (t == 0) *flag = (red[0] + red[1] + red[2] + red[3] >= 448) ? 1 : 0;
}

// ---------------------------------------------------------------------------
// Canonicalize float tensors to bf16, vectorized.
// ---------------------------------------------------------------------------
struct CT { const void* src[20]; int n[20]; int off[20]; };
__global__ __launch_bounds__(256) void conv_k(CT ct, u16* __restrict__ dstBase,
                                              const int* __restrict__ flag) {
    const int isbf = *flag;
    const int gid = blockIdx.x * 256 + threadIdx.x;
    const int stride = gridDim.x * 256;
    for (int tn = 0; tn < 20; ++tn) {
        const int n = ct.n[tn];
        const int n4 = n >> 2;
        u16* dst = dstBase + ct.off[tn];
        if (!isbf) {
            const float* s = (const float*)ct.src[tn];
            for (int i = gid; i < n4; i += stride) {
                f32x4 v = *(const f32x4*)(s + i * 4);
                *(ushort4*)(dst + i * 4) =
                    make_ushort4(f2bf(v[0]), f2bf(v[1]), f2bf(v[2]), f2bf(v[3]));
            }
            if (gid < (n & 3)) { int i = n4 * 4 + gid; dst[i] = f2bf(s[i]); }
        } else {
            const u16* s = (const u16*)ct.src[tn];
            for (int i = gid; i < n4; i += stride)
                *(ushort4*)(dst + i * 4) = *(const ushort4*)(s + i * 4);
            if (gid < (n & 3)) { int i = n4 * 4 + gid; dst[i] = s[i]; }
        }
    }
}

// ---------------------------------------------------------------------------
// Batched GEMM: C[z][m][n] = epi( sum_k A[z][m][k] * Bw[z][n][k] )
// 128x128 tile, BK=64, 4 waves, mfma_f32_16x16x32_bf16, XOR-swizzled LDS.
// global_load_lds(16B) staging + single-barrier LDS double-buffer:
//   iter k: issue async loads tile k+1 -> buf[nxt]; ds_read+MFMA buf[cur];
//   one __syncthreads (drains vmcnt: tile k+1 ready; protects buf reuse).
// Grid: x = z*nt + nTile (XCD swizzle: same-weight m-blocks on one XCD),
//       y = m-tile.
// ---------------------------------------------------------------------------
struct GP {
    const u16* A;  long lda; long aOff[16];
    const u16* Bw; long ldb; long bwOff[16];
    const u16* bias; long biasOff[16];
    const u16* add; long ldadd; long addOff;    // EPI 1/7
    const float* gate;                           // EPI 3
    void* C; long ldc; long cOff[16];
    float* C2;                                   // EPI 4: h f32
    u16* C3;                                     // EPI 4: summ_b
    int K; int nt;
};

template<int EPI>
__global__ __launch_bounds__(256) void gemm_k(GP p) {
    __shared__ __align__(16) u16 lA[2][128 * 64];   // 64 KB total w/ lB
    __shared__ __align__(16) u16 lB[2][128 * 64];
    const int t    = threadIdx.x;
    const int lane = t & 63;
    const int wv   = t >> 6;
    const int bx   = blockIdx.x;
    const int z    = bx / p.nt;
    const int n0   = (bx - z * p.nt) * 128;
    const int m0   = blockIdx.y * 128;

    const u16* Ab = p.A + p.aOff[z] + (long)m0 * p.lda;
    const u16* Bb = p.Bw + p.bwOff[z] + (long)n0 * p.ldb;

    f32x4 acc[4][4];
#pragma unroll
    for (int i = 0; i < 4; i++)
#pragma unroll
        for (int j = 0; j < 4; j++) acc[i][j] = (f32x4){0.f, 0.f, 0.f, 0.f};

    const int wm   = (wv & 1) * 64;
    const int wn   = (wv >> 1) * 64;
    const int fr   = lane & 15;
    const int quad = lane >> 4;

    // Staging map: LDS[row][c8] = Global[row][c8 ^ (row&7)]  (XOR bank swizzle)
    int rowA[4], src8A[4];
#pragma unroll
    for (int it = 0; it < 4; ++it) {
        int flat = it * 256 + t;
        rowA[it] = flat >> 3;
        src8A[it] = (flat & 7) ^ (rowA[it] & 7);
    }

    const int nk = p.K >> 6;
    // prologue: stage tile 0 into buf 0
#pragma unroll
    for (int it = 0; it < 4; ++it) {
        gload_lds16(Ab + (long)rowA[it] * p.lda + src8A[it] * 8,
                    &lA[0][(it * 256 + t) * 8]);
        gload_lds16(Bb + (long)rowA[it] * p.ldb + src8A[it] * 8,
                    &lB[0][(it * 256 + t) * 8]);
    }
    __syncthreads();

    for (int kt = 0; kt < nk; ++kt) {
        const int cur = kt & 1, nxt = cur ^ 1;
        if (kt + 1 < nk) {                       // async stage tile k+1
            const long kb = (long)(kt + 1) * 64;
#pragma unroll
            for (int it = 0; it < 4; ++it) {
                gload_lds16(Ab + (long)rowA[it] * p.lda + kb + src8A[it] * 8,
                            &lA[nxt][(it * 256 + t) * 8]);
                gload_lds16(Bb + (long)rowA[it] * p.ldb + kb + src8A[it] * 8,
                            &lB[nxt][(it * 256 + t) * 8]);
            }
        }
#pragma unroll
        for (int kk = 0; kk < 2; ++kk) {
            const int q = kk * 4 + quad;
            short8 aF[4], bF[4];
#pragma unroll
            for (int mi = 0; mi < 4; mi++) {
                int row = wm + mi * 16 + fr;
                aF[mi] = *(const short8*)&lA[cur][row * 64 + (q ^ (row & 7)) * 8];
            }
#pragma unroll
            for (int ni = 0; ni < 4; ni++) {
                int row = wn + ni * 16 + fr;
                bF[ni] = *(const short8*)&lB[cur][row * 64 + (q ^ (row & 7)) * 8];
            }
#pragma unroll
            for (int mi = 0; mi < 4; mi++)
#pragma unroll
                for (int ni = 0; ni < 4; ni++)
                    acc[mi][ni] = __builtin_amdgcn_mfma_f32_16x16x32_bf16(
                        aF[mi], bF[ni], acc[mi][ni], 0, 0, 0);
        }
        __syncthreads();   // drains vmcnt (tile k+1 ready) + buf-reuse safety
    }

    // Epilogue: D row = quad*4+reg, col = lane&15
#pragma unroll
    for (int mi = 0; mi < 4; mi++) {
#pragma unroll
        for (int ni = 0; ni < 4; ni++) {
            const int mg = m0 + wm + mi * 16 + quad * 4;
            const int ng = n0 + wn + ni * 16 + fr;
#pragma unroll
            for (int r = 0; r < 4; r++) {
                float v = acc[mi][ni][r];
                const long row = mg + r;
                if (EPI == 1) {        // tanh(acc+add+bias) -> bf16   [link]
                    float ad = bf2f(p.add[z * p.addOff + row * p.ldadd + ng]);
                    v = tanhf(v + ad + bf2f(p.bias[p.biasOff[z] + ng]));
                    ((u16*)p.C)[p.cOff[z] + row * p.ldc + ng] = f2bf(v);
                } else if (EPI == 3) { // gate*tanh(acc+bias) -> bf16  [upd]
                    v = tanhf(v + bf2f(p.bias[p.biasOff[z] + ng]));
                    v *= p.gate[row * 8 + z];
                    ((u16*)p.C)[p.cOff[z] + row * p.ldc + ng] = f2bf(v);
                } else if (EPI == 4) { // encode mix: h_b, summ_b, h(f32)
                    v = tanhf(v + bf2f(p.bias[ng]));
                    u16 b = f2bf(v);
                    ((u16*)p.C)[row * 512 + ng] = b;
                    p.C3[row * 512 + ng] = b;
                    p.C2[row * 512 + ng] = v;
                } else if (EPI == 6) { // (acc+bias) -> bf16           [cin, gih]
                    v = v + bf2f(p.bias[p.biasOff[z] + ng]);
                    ((u16*)p.C)[p.cOff[z] + row * p.ldc + ng] = f2bf(v);
                } else {               // EPI 7: tanh(acc+add) -> bf16 [f0]
                    float ad = bf2f(p.add[row * p.ldadd + ng]);
                    v = tanhf(v + ad);
                    ((u16*)p.C)[row * p.ldc + ng] = f2bf(v);
                }
            }
        }
    }
}

// ---------------------------------------------------------------------------
// Encode: masked mean / masked max / last token -> cat [B,1536]
// ---------------------------------------------------------------------------
__global__ __launch_bounds__(256) void encode_k(const int* __restrict__ x,
                                                const u16* __restrict__ embed,
                                                u16* __restrict__ cat) {
    __shared__ int toks[128];
    __shared__ int cnt_s;
    const int b = blockIdx.x, t = threadIdx.x;
    if (t < 128) toks[t] = x[b * 128 + t];
    __syncthreads();
    if (t == 0) {
        int c = 0;
        for (int l = 0; l < 128; l++) c += (toks[l] != 0);
        cnt_s = c;
    }
    __syncthreads();
    const int cnt = cnt_s;
    const int lastTok = toks[cnt > 0 ? cnt - 1 : 0];
    for (int w = t; w < 512; w += 256) {
        float sum = 0.f, mx = -10000.f;
        for (int l = 0; l < 128; l++) {
            int tok = toks[l];
            if (tok != 0) {
                float e = bf2f(embed[tok * 512 + w]);
                sum += e;
                mx = fmaxf(mx, e);
            }
        }
        float mean = sum / (float)(cnt > 0 ? cnt : 1);
        float last = bf2f(embed[lastTok * 512 + w]);
        cat[(long)b * 1536 + w]        = f2bf(mean);
        cat[(long)b * 1536 + 512 + w]  = f2bf(mx);
        cat[(long)b * 1536 + 1024 + w] = f2bf(last);
    }
}

// ---------------------------------------------------------------------------
// Fused GRU + gate-dot + prismion. gih bf16 [B, 16*1536]: z<8 = gi, z>=8 = gh.
// ---------------------------------------------------------------------------
__global__ __launch_bounds__(128) void gru_k(const u16* __restrict__ gih,
                                             float* __restrict__ hs,
                                             u16* __restrict__ hs_b,
                                             u16* __restrict__ prism,
                                             float* __restrict__ gate,
                                             const u16* __restrict__ Wg,
                                             const u16* __restrict__ bg,
                                             const u16* __restrict__ phase,
                                             const u16* __restrict__ pgain) {
    const int bs = blockIdx.x;
    const int b = bs >> 3, s = bs & 7;
    const int t = threadIdx.x;
    const int w = t * 4;
    const long gbase = (long)b * 24576 + s * 1536;
    const long hbase = (long)b * 4096 + s * 512;

    U4 ir, iz, in_, hr, hz, hn;
    ir.v  = *(const ushort4*)(gih + gbase + w);
    iz.v  = *(const ushort4*)(gih + gbase + 512 + w);
    in_.v = *(const ushort4*)(gih + gbase + 1024 + w);
    hr.v  = *(const ushort4*)(gih + gbase + 12288 + w);
    hz.v  = *(const ushort4*)(gih + gbase + 12288 + 512 + w);
    hn.v  = *(const ushort4*)(gih + gbase + 12288 + 1024 + w);
    f32x4 h = *(const f32x4*)(hs + hbase + w);

    float gpart = 0.f;
    f32x4 hnew;
    u16 hb[4], pb[4];
#pragma unroll
    for (int i = 0; i < 4; i++) {
        float r  = sigmoidf_(bf2f(ir.e[i]) + bf2f(hr.e[i]));
        float zz = sigmoidf_(bf2f(iz.e[i]) + bf2f(hz.e[i]));
        float n  = tanhf(bf2f(in_.e[i]) + r * bf2f(hn.e[i]));
        float hv = (1.f - zz) * n + zz * h[i];
        hnew[i] = hv;
        hb[i] = f2bf(hv);
        gpart += bf2f(Wg[s * 512 + w + i]) * hv;
        float ph = bf2f(phase[s * 512 + w + i]);
        float pg = bf2f(pgain[s * 512 + w + i]);
        float gain = (pg > 20.f) ? pg : log1pf(expf(pg));
        float c = cosf(hv + ph);
        pb[i] = f2bf(c * c * gain);
    }
    *(f32x4*)(hs + hbase + w) = hnew;
    *(ushort4*)(hs_b + hbase + w)  = make_ushort4(hb[0], hb[1], hb[2], hb[3]);
    *(ushort4*)(prism + hbase + w) = make_ushort4(pb[0], pb[1], pb[2], pb[3]);

#pragma unroll
    for (int off = 32; off; off >>= 1) gpart += __shfl_down(gpart, off, 64);
    __shared__ float red[2];
    if ((t & 63) == 0) red[t >> 6] = gpart;
    __syncthreads();
    if (t == 0) gate[bs] = sigmoidf_(red[0] + red[1] + bf2f(bg[s]));
}

// ---------------------------------------------------------------------------
// delta = sum_s upd / sqrt(S);  h = tanh(h*decay + delta); h_b = bf16(h)
// ---------------------------------------------------------------------------
__global__ __launch_bounds__(256) void hupd_k(const u16* __restrict__ upd,
                                              float* __restrict__ h,
                                              u16* __restrict__ h_b,
                                              const u16* __restrict__ decay_p) {
    const int idx = blockIdx.x * 256 + threadIdx.x;
    const int b = idx >> 9, w = idx & 511;
    const long base = (long)b * 4096 + w;
    float dsum = 0.f;
#pragma unroll
    for (int s = 0; s < 8; s++) dsum += bf2f(upd[base + s * 512]);
    const float decay = sigmoidf_(bf2f(decay_p[0]));
    const float hv = tanhf(h[idx] * decay + dsum * 0.35355339059327373f);
    h[idx] = hv;
    h_b[idx] = f2bf(hv);
}

// ---------------------------------------------------------------------------
// Final head; output dtype follows detected input dtype.
// ---------------------------------------------------------------------------
__global__ __launch_bounds__(64) void out_k(const float* __restrict__ h,
                                            const u16* __restrict__ Wout,
                                            const u16* __restrict__ bout,
                                            void* __restrict__ out,
                                            const int* __restrict__ flag) {
    const int b = blockIdx.x, lane = threadIdx.x;
    const int isbf = *flag;
    for (int j = 0; j < 10; j++) {
        float p = 0.f;
#pragma unroll
        for (int k = 0; k < 8; k++) {
            int w = lane + k * 64;
            p += h[(long)b * 512 + w] * bf2f(Wout[j * 512 + w]);
        }
#pragma unroll
        for (int off = 32; off; off >>= 1) p += __shfl_down(p, off, 64);
        if (lane == 0) {
            float val = p + bf2f(bout[j]);
            if (isbf) ((u16*)out)[b * 10 + j] = f2bf(val);
            else      ((float*)out)[b * 10 + j] = val;
        }
    }
}

// ---------------------------------------------------------------------------
extern "C" void kernel_launch(void* const* d_in, const int* in_sizes, int n_in,
                              void* d_out, int out_size, void* d_ws, size_t ws_size,
                              hipStream_t stream) {
    (void)n_in; (void)out_size; (void)ws_size;
    const int* x = (const int*)d_in[0];

    char* pp = (char*)d_ws;
    auto carve = [&](size_t n) { char* r = pp; pp += (n + 255) & ~(size_t)255; return (void*)r; };

    // canonical bf16 parameter block (~44 MB)
    CT ct;
    size_t ctot = 0;
    for (int i = 0; i < 20; i++) {
        ct.src[i] = d_in[i + 1];
        ct.n[i]   = in_sizes[i + 1];
        ct.off[i] = (int)ctot;
        ctot += ((size_t)in_sizes[i + 1] + 15) & ~(size_t)15;
    }
    u16* canon = (u16*)carve(ctot * 2);
    const u16* embed  = canon + ct.off[0];
    const u16* W_mix  = canon + ct.off[1];
    const u16* b_mix  = canon + ct.off[2];
    const u16* W_in   = canon + ct.off[3];
    const u16* b_in   = canon + ct.off[4];
    const u16* W_link = canon + ct.off[5];
    const u16* b_link = canon + ct.off[6];
    const u16* W_ih   = canon + ct.off[7];
    const u16* b_ih   = canon + ct.off[8];
    const u16* W_hh   = canon + ct.off[9];
    const u16* b_hh   = canon + ct.off[10];
    const u16* W_gate = canon + ct.off[11];
    const u16* b_gate = canon + ct.off[12];
    const u16* phase  = canon + ct.off[13];
    const u16* pgain  = canon + ct.off[14];
    const u16* W_delta= canon + ct.off[15];
    const u16* b_delta= canon + ct.off[16];
    const u16* decayp = canon + ct.off[17];
    const u16* W_out  = canon + ct.off[18];
    const u16* b_out  = canon + ct.off[19];

    int*   flag   = (int*)  carve(256);
    u16*   cat    = (u16*)  carve((size_t)1024 * 1536 * 2);
    u16*   h_b    = (u16*)  carve((size_t)1024 * 512 * 2);
    u16*   summ_b = (u16*)  carve((size_t)1024 * 512 * 2);
    float* h      = (float*)carve((size_t)1024 * 512 * 4);
    u16*   cin    = (u16*)  carve((size_t)1024 * 4096 * 2);
    u16*   f0     = (u16*)  carve((size_t)1024 * 4096 * 2);
    u16*   feats  = (u16*)  carve((size_t)1024 * 4096 * 2);
    float* hs     = (float*)carve((size_t)1024 * 4096 * 4);
    u16*   hs_b   = (u16*)  carve((size_t)1024 * 4096 * 2);
    u16*   gih    = (u16*)  carve((size_t)1024 * 24576 * 2);
    u16*   prism  = (u16*)  carve((size_t)1024 * 4096 * 2);
    u16*   upd    = (u16*)  carve((size_t)1024 * 4096 * 2);
    float* gate   = (float*)carve((size_t)1024 * 8 * 4);

    (void)hipMemsetAsync(hs,   0, (size_t)1024 * 4096 * 4, stream);
    (void)hipMemsetAsync(hs_b, 0, (size_t)1024 * 4096 * 2, stream);

    detect_k<<<dim3(1), dim3(256), 0, stream>>>((const u16*)d_in[1], flag);
    conv_k<<<dim3(1024), dim3(256), 0, stream>>>(ct, canon, flag);
    encode_k<<<dim3(1024), dim3(256), 0, stream>>>(x, embed, cat);

    {   // summary = tanh(cat @ W_mix^T + b_mix) -> h_b, summ_b, h
        GP p{}; p.A = cat; p.lda = 1536; p.Bw = W_mix; p.ldb = 1536;
        p.bias = b_mix; p.C = h_b; p.ldc = 512; p.C2 = h; p.C3 = summ_b;
        p.K = 1536; p.nt = 4;
        gemm_k<4><<<dim3(4, 8, 1), dim3(256), 0, stream>>>(p);
    }
    {   // cin = summary @ W_in[:, :, 512:]^T + b_in   (loop-invariant half)
        GP p{}; p.A = summ_b; p.lda = 512; p.Bw = W_in + 512; p.ldb = 1024;
        p.bias = b_in; p.C = cin; p.ldc = 4096; p.K = 512; p.nt = 32;
        gemm_k<6><<<dim3(32, 8, 1), dim3(256), 0, stream>>>(p);
    }

    for (int step = 0; step < 12; ++step) {
        {   // f0 = tanh(h @ W_in[:, :, :512]^T + cin)
            GP p{}; p.A = h_b; p.lda = 512; p.Bw = W_in; p.ldb = 1024;
            p.add = cin; p.ldadd = 4096; p.C = f0; p.ldc = 4096;
            p.K = 512; p.nt = 32;
            gemm_k<7><<<dim3(32, 8, 1), dim3(256), 0, stream>>>(p);
        }
        {   // feats = tanh(f0 + prev @ W_link^T + b_link)
            GP p{}; p.A = f0; p.lda = 4096;
            for (int s = 0; s < 8; s++) p.aOff[s] = (long)((s + 7) & 7) * 512;
            p.Bw = W_link; p.ldb = 512;
            for (int s = 0; s < 8; s++) p.bwOff[s] = (long)s * 512 * 512;
            p.bias = b_link;
            for (int s = 0; s < 8; s++) p.biasOff[s] = (long)s * 512;
            p.add = f0; p.ldadd = 4096; p.addOff = 512;
            p.C = feats; p.ldc = 4096;
            for (int s = 0; s < 8; s++) p.cOff[s] = (long)s * 512;
            p.K = 512; p.nt = 4;
            gemm_k<1><<<dim3(32, 8, 1), dim3(256), 0, stream>>>(p);
        }
        {   // gih: z<8 -> gi = feats@W_ih^T+b_ih ; z>=8 -> gh = hs_b@W_hh^T+b_hh
            GP p{}; p.A = feats; p.lda = 4096;
            p.Bw = W_ih; p.ldb = 512;
            p.bias = b_ih;
            p.C = gih; p.ldc = 24576;
            for (int zz = 0; zz < 16; zz++) {
                if (zz < 8) {
                    p.aOff[zz]  = (long)zz * 512;
                    p.bwOff[zz] = (long)zz * 1536 * 512;
                    p.biasOff[zz] = (long)zz * 1536;
                } else {
                    p.aOff[zz]  = (long)(hs_b - feats) + (long)(zz - 8) * 512;
                    p.bwOff[zz] = (long)(W_hh - W_ih) + (long)(zz - 8) * 1536 * 512;
                    p.biasOff[zz] = (long)(b_hh - b_ih) + (long)(zz - 8) * 1536;
                }
                p.cOff[zz] = (long)zz * 1536;
            }
            p.K = 512; p.nt = 12;
            gemm_k<6><<<dim3(192, 8, 1), dim3(256), 0, stream>>>(p);
        }
        gru_k<<<dim3(8192), dim3(128), 0, stream>>>(gih, hs, hs_b, prism, gate,
                                                    W_gate, b_gate, phase, pgain);
        {   // upd = gate * tanh(prism @ W_delta^T + b_delta) -> bf16
            GP p{}; p.A = prism; p.lda = 4096;
            for (int s = 0; s < 8; s++) p.aOff[s] = (long)s * 512;
            p.Bw = W_delta; p.ldb = 512;
            for (int s = 0; s < 8; s++) p.bwOff[s] = (long)s * 512 * 512;
            p.bias = b_delta;
            for (int s = 0; s < 8; s++) p.biasOff[s] = (long)s * 512;
            p.gate = gate;
            p.C = upd; p.ldc = 4096;
            for (int s = 0; s < 8; s++) p.cOff[s] = (long)s * 512;
            p.K = 512; p.nt = 4;
            gemm_k<3><<<dim3(32, 8, 1), dim3(256), 0, stream>>>(p);
        }
        hupd_k<<<dim3(2048), dim3(256), 0, stream>>>(upd, h, h_b, decayp);
    }

    out_k<<<dim3(1024), dim3(64), 0, stream>>>(h, W_out, b_out, d_out, flag);
}

// Round 8
// 2133.178 us; speedup vs baseline: 1.5259x; 1.2045x over previous
//
#include <hip/hip_runtime.h>
#include <hip/hip_bf16.h>

// B=1024, L=128, W=512, S=8, STEPS=12, VOCAB=32, NLAB=10

typedef unsigned short u16;
typedef __attribute__((ext_vector_type(8))) short short8;   // 8 x bf16
typedef __attribute__((ext_vector_type(4))) float f32x4;

__device__ __forceinline__ float bf2f(u16 v) {
    union { unsigned int u; float f; } x; x.u = ((unsigned int)v) << 16; return x.f;
}
__device__ __forceinline__ u16 f2bf(float f) {
    union { float f; unsigned int u; } x; x.f = f;
    unsigned int u = x.u;
    return (u16)((u + 0x7FFFu + ((u >> 16) & 1u)) >> 16);   // RNE
}
__device__ __forceinline__ float sigmoidf_(float v) { return 1.f / (1.f + expf(-v)); }

union U4 { ushort4 v; u16 e[4]; };

// Async global->LDS, 16B/lane. LDS dest = wave-uniform base + lane*16.
__device__ __forceinline__ void gload_lds16(const u16* g, u16* l) {
    __builtin_amdgcn_global_load_lds(
        (const __attribute__((address_space(1))) unsigned int*)g,
        (__attribute__((address_space(3))) unsigned int*)l, 16, 0, 0);
}

// ---------------------------------------------------------------------------
// Input-dtype detection (bf16 vs f32 inputs).
// ---------------------------------------------------------------------------
__device__ __forceinline__ int sane16(u16 u) {
    if ((u & 0x7FFF) == 0) return 1;
    int e = (u >> 7) & 0xFF;
    return (e >= 0x33 && e <= 0x43) ? 1 : 0;
}
__global__ __launch_bounds__(256) void detect_k(const u16* __restrict__ raw,
                                                int* __restrict__ flag) {
    const int t = threadIdx.x;
    int c = sane16(raw[1024 + t * 2]) + sane16(raw[1024 + t * 2 + 1]);
#pragma unroll
    for (int off = 32; off; off >>= 1) c += __shfl_down(c, off, 64);
    __shared__ int red[4];
    if ((t & 63) == 0) red[t >> 6] = c;
    __syncthreads();
    if (t == 0) *flag = (red[0] + red[1] + red[2] + red[3] >= 448) ? 1 : 0;
}

// ---------------------------------------------------------------------------
// Canonicalize float tensors to bf16, vectorized.
// ---------------------------------------------------------------------------
struct CT { const void* src[20]; int n[20]; int off[20]; };
__global__ __launch_bounds__(256) void conv_k(CT ct, u16* __restrict__ dstBase,
                                              const int* __restrict__ flag) {
    const int isbf = *flag;
    const int gid = blockIdx.x * 256 + threadIdx.x;
    const int stride = gridDim.x * 256;
    for (int tn = 0; tn < 20; ++tn) {
        const int n = ct.n[tn];
        const int n4 = n >> 2;
        u16* dst = dstBase + ct.off[tn];
        if (!isbf) {
            const float* s = (const float*)ct.src[tn];
            for (int i = gid; i < n4; i += stride) {
                f32x4 v = *(const f32x4*)(s + i * 4);
                *(ushort4*)(dst + i * 4) =
                    make_ushort4(f2bf(v[0]), f2bf(v[1]), f2bf(v[2]), f2bf(v[3]));
            }
            if (gid < (n & 3)) { int i = n4 * 4 + gid; dst[i] = f2bf(s[i]); }
        } else {
            const u16* s = (const u16*)ct.src[tn];
            for (int i = gid; i < n4; i += stride)
                *(ushort4*)(dst + i * 4) = *(const ushort4*)(s + i * 4);
            if (gid < (n & 3)) { int i = n4 * 4 + gid; dst[i] = s[i]; }
        }
    }
}

// ---------------------------------------------------------------------------
// Pack Wcat[s][g][0:512]=W_ih[s][g][:], [512:1024]=W_hh[s][g][:]  (one-time)
// ---------------------------------------------------------------------------
__global__ __launch_bounds__(256) void pack_k(const u16* __restrict__ Wih,
                                              const u16* __restrict__ Whh,
                                              u16* __restrict__ Wcat) {
    long i = ((long)blockIdx.x * 256 + threadIdx.x) * 8;   // over 8*1536*512
    if (i >= 8L * 1536 * 512) return;
    long sg = i >> 9;
    long k  = i & 511;
    *(short8*)(Wcat + sg * 1024 + k)       = *(const short8*)(Wih + i);
    *(short8*)(Wcat + sg * 1024 + 512 + k) = *(const short8*)(Whh + i);
}

// ---------------------------------------------------------------------------
// Batched GEMM, MT x 128 tile, BK=64, single-barrier LDS double-buffer with
// global_load_lds staging (R7-proven structure). MT in {64,128}.
// ---------------------------------------------------------------------------
struct GP {
    const u16* A;  long lda; long aOff[8];
    const u16* Bw; long ldb; long bwOff[8];
    const u16* bias; long biasOff[8];
    const u16* add; long ldadd; long addOff;
    const float* gate_pre;                      // EPI 3
    const u16* bgate;                           // EPI 3
    void* C; long ldc; long cOff[8];
    float* C2;                                  // EPI 4
    u16* C3;                                    // EPI 4
    int K; int nt;
};

template<int EPI, int MT>
__global__ __launch_bounds__(256) void gemm_k(GP p) {
    constexpr int MW   = MT / 32;   // m-tiles per wave
    constexpr int AITS = MT / 32;   // A staging iterations
    __shared__ __align__(16) u16 lA[2][MT * 64];
    __shared__ __align__(16) u16 lB[2][128 * 64];
    const int t    = threadIdx.x;
    const int lane = t & 63;
    const int wv   = t >> 6;
    const int bx   = blockIdx.x;
    const int z    = bx / p.nt;
    const int n0   = (bx - z * p.nt) * 128;
    const int m0   = blockIdx.y * MT;

    const u16* Ab = p.A + p.aOff[z] + (long)m0 * p.lda;
    const u16* Bb = p.Bw + p.bwOff[z] + (long)n0 * p.ldb;

    f32x4 acc[MW][4];
#pragma unroll
    for (int i = 0; i < MW; i++)
#pragma unroll
        for (int j = 0; j < 4; j++) acc[i][j] = (f32x4){0.f, 0.f, 0.f, 0.f};

    const int wm   = (wv & 1) * (MT / 2);
    const int wn   = (wv >> 1) * 64;
    const int fr   = lane & 15;
    const int quad = lane >> 4;

    // LDS[row][c8] = Global[row][c8 ^ (row&7)]  (XOR bank swizzle, 8-half chunks)
    const int nk = p.K >> 6;
#pragma unroll
    for (int it = 0; it < AITS; ++it) {
        int flat = it * 256 + t, row = flat >> 3, src = (flat & 7) ^ (row & 7);
        gload_lds16(Ab + (long)row * p.lda + src * 8, &lA[0][flat * 8]);
    }
#pragma unroll
    for (int it = 0; it < 4; ++it) {
        int flat = it * 256 + t, row = flat >> 3, src = (flat & 7) ^ (row & 7);
        gload_lds16(Bb + (long)row * p.ldb + src * 8, &lB[0][flat * 8]);
    }
    __syncthreads();

    for (int kt = 0; kt < nk; ++kt) {
        const int cur = kt & 1, nxt = cur ^ 1;
        if (kt + 1 < nk) {
            const long kb = (long)(kt + 1) * 64;
#pragma unroll
            for (int it = 0; it < AITS; ++it) {
                int flat = it * 256 + t, row = flat >> 3, src = (flat & 7) ^ (row & 7);
                gload_lds16(Ab + (long)row * p.lda + kb + src * 8, &lA[nxt][flat * 8]);
            }
#pragma unroll
            for (int it = 0; it < 4; ++it) {
                int flat = it * 256 + t, row = flat >> 3, src = (flat & 7) ^ (row & 7);
                gload_lds16(Bb + (long)row * p.ldb + kb + src * 8, &lB[nxt][flat * 8]);
            }
        }
#pragma unroll
        for (int kk = 0; kk < 2; ++kk) {
            const int q = kk * 4 + quad;
            short8 aF[MW], bF[4];
#pragma unroll
            for (int mi = 0; mi < MW; mi++) {
                int row = wm + mi * 16 + fr;
                aF[mi] = *(const short8*)&lA[cur][row * 64 + (q ^ (row & 7)) * 8];
            }
#pragma unroll
            for (int ni = 0; ni < 4; ni++) {
                int row = wn + ni * 16 + fr;
                bF[ni] = *(const short8*)&lB[cur][row * 64 + (q ^ (row & 7)) * 8];
            }
#pragma unroll
            for (int mi = 0; mi < MW; mi++)
#pragma unroll
                for (int ni = 0; ni < 4; ni++)
                    acc[mi][ni] = __builtin_amdgcn_mfma_f32_16x16x32_bf16(
                        aF[mi], bF[ni], acc[mi][ni], 0, 0, 0);
        }
        __syncthreads();
    }

    // Epilogue: D row = quad*4+reg, col = lane&15
#pragma unroll
    for (int mi = 0; mi < MW; mi++) {
#pragma unroll
        for (int ni = 0; ni < 4; ni++) {
            const int mg = m0 + wm + mi * 16 + quad * 4;
            const int ng = n0 + wn + ni * 16 + fr;
#pragma unroll
            for (int r = 0; r < 4; r++) {
                float v = acc[mi][ni][r];
                const long row = mg + r;
                if (EPI == 1) {        // tanh(acc+add+bias) -> bf16   [link->fhs]
                    float ad = bf2f(p.add[z * p.addOff + row * p.ldadd + ng]);
                    v = tanhf(v + ad + bf2f(p.bias[p.biasOff[z] + ng]));
                    ((u16*)p.C)[p.cOff[z] + row * p.ldc + ng] = f2bf(v);
                } else if (EPI == 3) { // sig(gate_pre+bg)*tanh(acc+bias) [upd]
                    v = tanhf(v + bf2f(p.bias[p.biasOff[z] + ng]));
                    v *= sigmoidf_(p.gate_pre[row * 8 + z] + bf2f(p.bgate[z]));
                    ((u16*)p.C)[p.cOff[z] + row * p.ldc + ng] = f2bf(v);
                } else if (EPI == 4) { // encode mix: h_b, summ_b, h(f32)
                    v = tanhf(v + bf2f(p.bias[ng]));
                    u16 b = f2bf(v);
                    ((u16*)p.C)[row * 512 + ng] = b;
                    p.C3[row * 512 + ng] = b;
                    p.C2[row * 512 + ng] = v;
                } else if (EPI == 6) { // (acc+bias) -> bf16            [cin]
                    v = v + bf2f(p.bias[p.biasOff[z] + ng]);
                    ((u16*)p.C)[p.cOff[z] + row * p.ldc + ng] = f2bf(v);
                } else {               // EPI 7: tanh(acc+add) -> bf16  [f0]
                    float ad = bf2f(p.add[row * p.ldadd + ng]);
                    v = tanhf(v + ad);
                    ((u16*)p.C)[row * p.ldc + ng] = f2bf(v);
                }
            }
        }
    }
}

// ---------------------------------------------------------------------------
// Fused GRU-GEMM: per block (64 b-rows, s, 128 w-cols) accumulate r,z,inn,hn
// via K=1024 concat A=[feats;hs_b] x Wcat=[W_ih|W_hh], then GRU + prismion +
// gate-partial in the epilogue. BK=32, double-buffered, 56 KB LDS.
// ---------------------------------------------------------------------------
struct GGP {
    const u16* fhs_in;    // [b][s][1024]  (feats | hs_b)
    u16* fhs_out;         // write hs_b' at [b][s][512+w]
    const u16* Wcat;      // [s][1536][1024]
    const u16* b_ih;      // [s][1536]
    const u16* b_hh;      // [s][1536]
    u16* prism;           // [b][s][512]
    float* gate_pre;      // [b][8]  (atomicAdd, pre-zeroed)
    const u16* Wg;        // [s][512]
    const u16* phase;     // [s][512]
    const u16* pgain;     // [s][512]
};

__global__ __launch_bounds__(256, 2) void grug_k(GGP p) {
    __shared__ __align__(16) u16 sA[2][64 * 32];        //  8 KB
    __shared__ __align__(16) u16 sW[2][3][128 * 32];    // 48 KB
    const int t    = threadIdx.x;
    const int lane = t & 63;
    const int wv   = t >> 6;
    const int s    = blockIdx.x >> 2;
    const int w0   = (blockIdx.x & 3) * 128;
    const int m0   = blockIdx.y * 64;
    const int fr   = lane & 15;
    const int quad = lane >> 4;
    const int wn   = wv * 32;          // wave's n-range (32 cols)

    const u16* Ab = p.fhs_in + (long)m0 * 8192 + s * 1024;
    const u16* Wb = p.Wcat + (long)s * 1536 * 1024;

    f32x4 acc[4][4][2];   // [q: r,z,inn,hn][mi 0..3][ni 0..1]
#pragma unroll
    for (int q = 0; q < 4; q++)
#pragma unroll
        for (int mi = 0; mi < 4; mi++)
#pragma unroll
            for (int ni = 0; ni < 2; ni++) acc[q][mi][ni] = (f32x4){0.f,0.f,0.f,0.f};

    // staging maps (4-half chunks per 32-col row, XOR swizzle period 4)
    const int arow = t >> 2, ac4 = t & 3, asrc = ac4 ^ (arow & 3);

    auto stageA = [&](int buf, long kb) {
        gload_lds16(Ab + (long)arow * 8192 + kb + asrc * 8, &sA[buf][t * 8]);
    };
    auto stageW = [&](int buf, long kb) {
#pragma unroll
        for (int q = 0; q < 3; q++)
#pragma unroll
            for (int it = 0; it < 2; ++it) {
                int flat = it * 256 + t, row = flat >> 2, src = (flat & 3) ^ (row & 3);
                long g = (long)(q * 512 + w0 + row);
                gload_lds16(Wb + g * 1024 + kb + src * 8, &sW[buf][q][flat * 8]);
            }
    };

    stageA(0, 0); stageW(0, 0);
    __syncthreads();

    for (int kt = 0; kt < 32; ++kt) {
        const int cur = kt & 1, nxt = cur ^ 1;
        if (kt + 1 < 32) { stageA(nxt, (long)(kt + 1) * 32); stageW(nxt, (long)(kt + 1) * 32); }
        const int qsel = (kt < 16) ? 2 : 3;   // inn (k<512) vs hn (k>=512)
        short8 aF[4], bF[3][2];
#pragma unroll
        for (int mi = 0; mi < 4; mi++) {
            int row = mi * 16 + fr;
            aF[mi] = *(const short8*)&sA[cur][row * 32 + ((quad ^ (row & 3)) & 3) * 8];
        }
#pragma unroll
        for (int q = 0; q < 3; q++)
#pragma unroll
            for (int ni = 0; ni < 2; ni++) {
                int row = wn + ni * 16 + fr;
                bF[q][ni] = *(const short8*)&sW[cur][q][row * 32 + ((quad ^ (row & 3)) & 3) * 8];
            }
#pragma unroll
        for (int mi = 0; mi < 4; mi++)
#pragma unroll
            for (int ni = 0; ni < 2; ni++) {
                acc[0][mi][ni] = __builtin_amdgcn_mfma_f32_16x16x32_bf16(aF[mi], bF[0][ni], acc[0][mi][ni], 0, 0, 0);
                acc[1][mi][ni] = __builtin_amdgcn_mfma_f32_16x16x32_bf16(aF[mi], bF[1][ni], acc[1][mi][ni], 0, 0, 0);
                if (qsel == 2)
                    acc[2][mi][ni] = __builtin_amdgcn_mfma_f32_16x16x32_bf16(aF[mi], bF[2][ni], acc[2][mi][ni], 0, 0, 0);
                else
                    acc[3][mi][ni] = __builtin_amdgcn_mfma_f32_16x16x32_bf16(aF[mi], bF[2][ni], acc[3][mi][ni], 0, 0, 0);
            }
        __syncthreads();
    }

    // Epilogue: GRU + prismion + gate partial
    const u16* bih = p.b_ih + (long)s * 1536;
    const u16* bhh = p.b_hh + (long)s * 1536;
    float gp[4][4];
#pragma unroll
    for (int mi = 0; mi < 4; mi++)
#pragma unroll
        for (int r = 0; r < 4; r++) gp[mi][r] = 0.f;

#pragma unroll
    for (int mi = 0; mi < 4; mi++) {
#pragma unroll
        for (int ni = 0; ni < 2; ni++) {
            const int col = w0 + wn + ni * 16 + fr;          // w in [0,512)
#pragma unroll
            for (int r = 0; r < 4; r++) {
                const long b = m0 + mi * 16 + quad * 4 + r;
                float rv = sigmoidf_(acc[0][mi][ni][r] + bf2f(bih[col]) + bf2f(bhh[col]));
                float zv = sigmoidf_(acc[1][mi][ni][r] + bf2f(bih[512 + col]) + bf2f(bhh[512 + col]));
                float nv = tanhf(acc[2][mi][ni][r] + bf2f(bih[1024 + col])
                                 + rv * (acc[3][mi][ni][r] + bf2f(bhh[1024 + col])));
                float hold = bf2f(p.fhs_in[b * 8192 + s * 1024 + 512 + col]);
                float hv = (1.f - zv) * nv + zv * hold;
                p.fhs_out[b * 8192 + s * 1024 + 512 + col] = f2bf(hv);
                float ph = bf2f(p.phase[s * 512 + col]);
                float pg = bf2f(p.pgain[s * 512 + col]);
                float gain = (pg > 20.f) ? pg : log1pf(expf(pg));
                float c = cosf(hv + ph);
                p.prism[b * 4096 + s * 512 + col] = f2bf(c * c * gain);
                gp[mi][r] += bf2f(p.Wg[s * 512 + col]) * hv;
            }
        }
    }
    // reduce over fr (16 lanes within quad), then one atomic per (row) from fr==0
#pragma unroll
    for (int m = 1; m < 16; m <<= 1)
#pragma unroll
        for (int mi = 0; mi < 4; mi++)
#pragma unroll
            for (int r = 0; r < 4; r++) gp[mi][r] += __shfl_xor(gp[mi][r], m, 64);
    if (fr == 0) {
#pragma unroll
        for (int mi = 0; mi < 4; mi++)
#pragma unroll
            for (int r = 0; r < 4; r++) {
                long b = m0 + mi * 16 + quad * 4 + r;
                atomicAdd(&p.gate_pre[b * 8 + s], gp[mi][r]);
            }
    }
}

// ---------------------------------------------------------------------------
// Encode: masked mean / masked max / last token -> cat [B,1536]
// ---------------------------------------------------------------------------
__global__ __launch_bounds__(256) void encode_k(const int* __restrict__ x,
                                                const u16* __restrict__ embed,
                                                u16* __restrict__ cat) {
    __shared__ int toks[128];
    __shared__ int cnt_s;
    const int b = blockIdx.x, t = threadIdx.x;
    if (t < 128) toks[t] = x[b * 128 + t];
    __syncthreads();
    if (t == 0) {
        int c = 0;
        for (int l = 0; l < 128; l++) c += (toks[l] != 0);
        cnt_s = c;
    }
    __syncthreads();
    const int cnt = cnt_s;
    const int lastTok = toks[cnt > 0 ? cnt - 1 : 0];
    for (int w = t; w < 512; w += 256) {
        float sum = 0.f, mx = -10000.f;
        for (int l = 0; l < 128; l++) {
            int tok = toks[l];
            if (tok != 0) {
                float e = bf2f(embed[tok * 512 + w]);
                sum += e;
                mx = fmaxf(mx, e);
            }
        }
        float mean = sum / (float)(cnt > 0 ? cnt : 1);
        float last = bf2f(embed[lastTok * 512 + w]);
        cat[(long)b * 1536 + w]        = f2bf(mean);
        cat[(long)b * 1536 + 512 + w]  = f2bf(mx);
        cat[(long)b * 1536 + 1024 + w] = f2bf(last);
    }
}

// ---------------------------------------------------------------------------
// delta = sum_s upd / sqrt(S);  h = tanh(h*decay + delta); h_b = bf16(h)
// ---------------------------------------------------------------------------
__global__ __launch_bounds__(256) void hupd_k(const u16* __restrict__ upd,
                                              float* __restrict__ h,
                                              u16* __restrict__ h_b,
                                              const u16* __restrict__ decay_p) {
    const int idx = blockIdx.x * 256 + threadIdx.x;
    const int b = idx >> 9, w = idx & 511;
    const long base = (long)b * 4096 + w;
    float dsum = 0.f;
#pragma unroll
    for (int s = 0; s < 8; s++) dsum += bf2f(upd[base + s * 512]);
    const float decay = sigmoidf_(bf2f(decay_p[0]));
    const float hv = tanhf(h[idx] * decay + dsum * 0.35355339059327373f);
    h[idx] = hv;
    h_b[idx] = f2bf(hv);
}

// ---------------------------------------------------------------------------
// Final head; output dtype follows detected input dtype.
// ---------------------------------------------------------------------------
__global__ __launch_bounds__(64) void out_k(const float* __restrict__ h,
                                            const u16* __restrict__ Wout,
                                            const u16* __restrict__ bout,
                                            void* __restrict__ out,
                                            const int* __restrict__ flag) {
    const int b = blockIdx.x, lane = threadIdx.x;
    const int isbf = *flag;
    for (int j = 0; j < 10; j++) {
        float p = 0.f;
#pragma unroll
        for (int k = 0; k < 8; k++) {
            int w = lane + k * 64;
            p += h[(long)b * 512 + w] * bf2f(Wout[j * 512 + w]);
        }
#pragma unroll
        for (int off = 32; off; off >>= 1) p += __shfl_down(p, off, 64);
        if (lane == 0) {
            float val = p + bf2f(bout[j]);
            if (isbf) ((u16*)out)[b * 10 + j] = f2bf(val);
            else      ((float*)out)[b * 10 + j] = val;
        }
    }
}

// ---------------------------------------------------------------------------
extern "C" void kernel_launch(void* const* d_in, const int* in_sizes, int n_in,
                              void* d_out, int out_size, void* d_ws, size_t ws_size,
                              hipStream_t stream) {
    (void)n_in; (void)out_size; (void)ws_size;
    const int* x = (const int*)d_in[0];

    char* pp = (char*)d_ws;
    auto carve = [&](size_t n) { char* r = pp; pp += (n + 255) & ~(size_t)255; return (void*)r; };

    // canonical bf16 parameter block (~44 MB)
    CT ct;
    size_t ctot = 0;
    for (int i = 0; i < 20; i++) {
        ct.src[i] = d_in[i + 1];
        ct.n[i]   = in_sizes[i + 1];
        ct.off[i] = (int)ctot;
        ctot += ((size_t)in_sizes[i + 1] + 15) & ~(size_t)15;
    }
    u16* canon = (u16*)carve(ctot * 2);
    const u16* embed  = canon + ct.off[0];
    const u16* W_mix  = canon + ct.off[1];
    const u16* b_mix  = canon + ct.off[2];
    const u16* W_in   = canon + ct.off[3];
    const u16* b_in   = canon + ct.off[4];
    const u16* W_link = canon + ct.off[5];
    const u16* b_link = canon + ct.off[6];
    const u16* W_ih   = canon + ct.off[7];
    const u16* b_ih   = canon + ct.off[8];
    const u16* W_hh   = canon + ct.off[9];
    const u16* b_hh   = canon + ct.off[10];
    const u16* W_gate = canon + ct.off[11];
    const u16* b_gate = canon + ct.off[12];
    const u16* phase  = canon + ct.off[13];
    const u16* pgain  = canon + ct.off[14];
    const u16* W_delta= canon + ct.off[15];
    const u16* b_delta= canon + ct.off[16];
    const u16* decayp = canon + ct.off[17];
    const u16* W_out  = canon + ct.off[18];
    const u16* b_out  = canon + ct.off[19];

    int*   flag   = (int*)  carve(256);
    u16*   Wcat   = (u16*)  carve((size_t)8 * 1536 * 1024 * 2);  // 25 MB
    u16*   cat    = (u16*)  carve((size_t)1024 * 1536 * 2);
    u16*   h_b    = (u16*)  carve((size_t)1024 * 512 * 2);
    u16*   summ_b = (u16*)  carve((size_t)1024 * 512 * 2);
    float* h      = (float*)carve((size_t)1024 * 512 * 4);
    u16*   cin    = (u16*)  carve((size_t)1024 * 4096 * 2);
    u16*   f0     = (u16*)  carve((size_t)1024 * 4096 * 2);
    u16*   fhs0   = (u16*)  carve((size_t)1024 * 8192 * 2);      // 16 MB
    u16*   fhs1   = (u16*)  carve((size_t)1024 * 8192 * 2);      // 16 MB
    u16*   prism  = (u16*)  carve((size_t)1024 * 4096 * 2);
    u16*   upd    = (u16*)  carve((size_t)1024 * 4096 * 2);
    float* gate_pre = (float*)carve((size_t)1024 * 8 * 4);

    (void)hipMemsetAsync(fhs0, 0, (size_t)1024 * 8192 * 2, stream);
    (void)hipMemsetAsync(fhs1, 0, (size_t)1024 * 8192 * 2, stream);

    detect_k<<<dim3(1), dim3(256), 0, stream>>>((const u16*)d_in[1], flag);
    conv_k<<<dim3(1024), dim3(256), 0, stream>>>(ct, canon, flag);
    pack_k<<<dim3(3072), dim3(256), 0, stream>>>(W_ih, W_hh, Wcat);
    encode_k<<<dim3(1024), dim3(256), 0, stream>>>(x, embed, cat);

    {   // summary = tanh(cat @ W_mix^T + b_mix) -> h_b, summ_b, h
        GP p{}; p.A = cat; p.lda = 1536; p.Bw = W_mix; p.ldb = 1536;
        p.bias = b_mix; p.C = h_b; p.ldc = 512; p.C2 = h; p.C3 = summ_b;
        p.K = 1536; p.nt = 4;
        gemm_k<4, 64><<<dim3(4, 16, 1), dim3(256), 0, stream>>>(p);
    }
    {   // cin = summary @ W_in[:, :, 512:]^T + b_in
        GP p{}; p.A = summ_b; p.lda = 512; p.Bw = W_in + 512; p.ldb = 1024;
        p.bias = b_in; p.C = cin; p.ldc = 4096; p.K = 512; p.nt = 32;
        gemm_k<6, 64><<<dim3(32, 16, 1), dim3(256), 0, stream>>>(p);
    }

    for (int step = 0; step < 12; ++step) {
        u16* fhs_cur = (step & 1) ? fhs1 : fhs0;
        u16* fhs_nxt = (step & 1) ? fhs0 : fhs1;
        {   // f0 = tanh(h @ W_in[:, :, :512]^T + cin)
            GP p{}; p.A = h_b; p.lda = 512; p.Bw = W_in; p.ldb = 1024;
            p.add = cin; p.ldadd = 4096; p.C = f0; p.ldc = 4096;
            p.K = 512; p.nt = 32;
            gemm_k<7, 64><<<dim3(32, 16, 1), dim3(256), 0, stream>>>(p);
        }
        {   // feats = tanh(f0 + prev @ W_link^T + b_link) -> fhs_cur[:, s, 0:512]
            GP p{}; p.A = f0; p.lda = 4096;
            for (int s = 0; s < 8; s++) p.aOff[s] = (long)((s + 7) & 7) * 512;
            p.Bw = W_link; p.ldb = 512;
            for (int s = 0; s < 8; s++) p.bwOff[s] = (long)s * 512 * 512;
            p.bias = b_link;
            for (int s = 0; s < 8; s++) p.biasOff[s] = (long)s * 512;
            p.add = f0; p.ldadd = 4096; p.addOff = 512;
            p.C = fhs_cur; p.ldc = 8192;
            for (int s = 0; s < 8; s++) p.cOff[s] = (long)s * 1024;
            p.K = 512; p.nt = 4;
            gemm_k<1, 64><<<dim3(32, 16, 1), dim3(256), 0, stream>>>(p);
        }
        (void)hipMemsetAsync(gate_pre, 0, (size_t)1024 * 8 * 4, stream);
        {   // fused GRU-GEMM
            GGP g{};
            g.fhs_in = fhs_cur; g.fhs_out = fhs_nxt; g.Wcat = Wcat;
            g.b_ih = b_ih; g.b_hh = b_hh; g.prism = prism; g.gate_pre = gate_pre;
            g.Wg = W_gate; g.phase = phase; g.pgain = pgain;
            grug_k<<<dim3(32, 16, 1), dim3(256), 0, stream>>>(g);
        }
        {   // upd = sig(gate)*tanh(prism @ W_delta^T + b_delta) -> bf16
            GP p{}; p.A = prism; p.lda = 4096;
            for (int s = 0; s < 8; s++) p.aOff[s] = (long)s * 512;
            p.Bw = W_delta; p.ldb = 512;
            for (int s = 0; s < 8; s++) p.bwOff[s] = (long)s * 512 * 512;
            p.bias = b_delta;
            for (int s = 0; s < 8; s++) p.biasOff[s] = (long)s * 512;
            p.gate_pre = gate_pre; p.bgate = b_gate;
            p.C = upd; p.ldc = 4096;
            for (int s = 0; s < 8; s++) p.cOff[s] = (long)s * 512;
            p.K = 512; p.nt = 4;
            gemm_k<3, 64><<<dim3(32, 16, 1), dim3(256), 0, stream>>>(p);
        }
        hupd_k<<<dim3(2048), dim3(256), 0, stream>>>(upd, h, h_b, decayp);
    }

    out_k<<<dim3(1024), dim3(64), 0, stream>>>(h, W_out, b_out, d_out, flag);
}

// Round 9
// 1536.384 us; speedup vs baseline: 2.1186x; 1.3884x over previous
//
#include <hip/hip_runtime.h>
#include <hip/hip_bf16.h>

// B=1024, L=128, W=512, S=8, STEPS=12, VOCAB=32, NLAB=10

typedef unsigned short u16;
typedef __attribute__((ext_vector_type(8))) short short8;   // 8 x bf16
typedef __attribute__((ext_vector_type(4))) float f32x4;

__device__ __forceinline__ float bf2f(u16 v) {
    union { unsigned int u; float f; } x; x.u = ((unsigned int)v) << 16; return x.f;
}
__device__ __forceinline__ u16 f2bf(float f) {
    union { float f; unsigned int u; } x; x.f = f;
    unsigned int u = x.u;
    return (u16)((u + 0x7FFFu + ((u >> 16) & 1u)) >> 16);   // RNE
}
// Fast transcendentals: v_exp/v_log/v_cos/v_rcp HW ops (~1e-6 err << bf16 eps)
__device__ __forceinline__ float fsig(float v) {
    return __builtin_amdgcn_rcpf(1.f + __expf(-v));
}
__device__ __forceinline__ float ftanh(float v) {
    return 1.f - 2.f * __builtin_amdgcn_rcpf(__expf(2.f * v) + 1.f);
}
__device__ __forceinline__ float fsoftplus(float v) {
    return (v > 20.f) ? v : __logf(1.f + __expf(v));
}

union U4 { ushort4 v; u16 e[4]; };

// Async global->LDS, 16B/lane. LDS dest = wave-uniform base + lane*16.
__device__ __forceinline__ void gload_lds16(const u16* g, u16* l) {
    __builtin_amdgcn_global_load_lds(
        (const __attribute__((address_space(1))) unsigned int*)g,
        (__attribute__((address_space(3))) unsigned int*)l, 16, 0, 0);
}

// ---------------------------------------------------------------------------
// Input-dtype detection (bf16 vs f32 inputs).
// ---------------------------------------------------------------------------
__device__ __forceinline__ int sane16(u16 u) {
    if ((u & 0x7FFF) == 0) return 1;
    int e = (u >> 7) & 0xFF;
    return (e >= 0x33 && e <= 0x43) ? 1 : 0;
}
__global__ __launch_bounds__(256) void detect_k(const u16* __restrict__ raw,
                                                int* __restrict__ flag) {
    const int t = threadIdx.x;
    int c = sane16(raw[1024 + t * 2]) + sane16(raw[1024 + t * 2 + 1]);
#pragma unroll
    for (int off = 32; off; off >>= 1) c += __shfl_down(c, off, 64);
    __shared__ int red[4];
    if ((t & 63) == 0) red[t >> 6] = c;
    __syncthreads();
    if (t == 0) *flag = (red[0] + red[1] + red[2] + red[3] >= 448) ? 1 : 0;
}

// ---------------------------------------------------------------------------
// Canonicalize float tensors to bf16, vectorized.
// ---------------------------------------------------------------------------
struct CT { const void* src[20]; int n[20]; int off[20]; };
__global__ __launch_bounds__(256) void conv_k(CT ct, u16* __restrict__ dstBase,
                                              const int* __restrict__ flag) {
    const int isbf = *flag;
    const int gid = blockIdx.x * 256 + threadIdx.x;
    const int stride = gridDim.x * 256;
    for (int tn = 0; tn < 20; ++tn) {
        const int n = ct.n[tn];
        const int n4 = n >> 2;
        u16* dst = dstBase + ct.off[tn];
        if (!isbf) {
            const float* s = (const float*)ct.src[tn];
            for (int i = gid; i < n4; i += stride) {
                f32x4 v = *(const f32x4*)(s + i * 4);
                *(ushort4*)(dst + i * 4) =
                    make_ushort4(f2bf(v[0]), f2bf(v[1]), f2bf(v[2]), f2bf(v[3]));
            }
            if (gid < (n & 3)) { int i = n4 * 4 + gid; dst[i] = f2bf(s[i]); }
        } else {
            const u16* s = (const u16*)ct.src[tn];
            for (int i = gid; i < n4; i += stride)
                *(ushort4*)(dst + i * 4) = *(const ushort4*)(s + i * 4);
            if (gid < (n & 3)) { int i = n4 * 4 + gid; dst[i] = s[i]; }
        }
    }
}

// ---------------------------------------------------------------------------
// Pack Wcat[s][g][0:512]=W_ih[s][g][:], [512:1024]=W_hh[s][g][:]  (one-time)
// ---------------------------------------------------------------------------
__global__ __launch_bounds__(256) void pack_k(const u16* __restrict__ Wih,
                                              const u16* __restrict__ Whh,
                                              u16* __restrict__ Wcat) {
    long i = ((long)blockIdx.x * 256 + threadIdx.x) * 8;   // over 8*1536*512
    if (i >= 8L * 1536 * 512) return;
    long sg = i >> 9;
    long k  = i & 511;
    *(short8*)(Wcat + sg * 1024 + k)       = *(const short8*)(Wih + i);
    *(short8*)(Wcat + sg * 1024 + 512 + k) = *(const short8*)(Whh + i);
}

// ---------------------------------------------------------------------------
// Batched GEMM, MT x 128 tile, BK=64, single-barrier LDS double-buffer with
// global_load_lds staging (R7-proven structure). MT in {64,128}.
// ---------------------------------------------------------------------------
struct GP {
    const u16* A;  long lda; long aOff[8];
    const u16* Bw; long ldb; long bwOff[8];
    const u16* bias; long biasOff[8];
    const u16* add; long ldadd; long addOff;
    const float* gate_pre;                      // EPI 3
    const u16* bgate;                           // EPI 3
    void* C; long ldc; long cOff[8];
    float* C2;                                  // EPI 4
    u16* C3;                                    // EPI 4
    int K; int nt;
};

template<int EPI, int MT>
__global__ __launch_bounds__(256) void gemm_k(GP p) {
    constexpr int MW   = MT / 32;   // m-tiles per wave
    constexpr int AITS = MT / 32;   // A staging iterations
    __shared__ __align__(16) u16 lA[2][MT * 64];
    __shared__ __align__(16) u16 lB[2][128 * 64];
    const int t    = threadIdx.x;
    const int lane = t & 63;
    const int wv   = t >> 6;
    const int bx   = blockIdx.x;
    const int z    = bx / p.nt;
    const int n0   = (bx - z * p.nt) * 128;
    const int m0   = blockIdx.y * MT;

    const u16* Ab = p.A + p.aOff[z] + (long)m0 * p.lda;
    const u16* Bb = p.Bw + p.bwOff[z] + (long)n0 * p.ldb;

    f32x4 acc[MW][4];
#pragma unroll
    for (int i = 0; i < MW; i++)
#pragma unroll
        for (int j = 0; j < 4; j++) acc[i][j] = (f32x4){0.f, 0.f, 0.f, 0.f};

    const int wm   = (wv & 1) * (MT / 2);
    const int wn   = (wv >> 1) * 64;
    const int fr   = lane & 15;
    const int quad = lane >> 4;

    // LDS[row][c8] = Global[row][c8 ^ (row&7)]  (XOR bank swizzle, 128B rows)
    const int nk = p.K >> 6;
#pragma unroll
    for (int it = 0; it < AITS; ++it) {
        int flat = it * 256 + t, row = flat >> 3, src = (flat & 7) ^ (row & 7);
        gload_lds16(Ab + (long)row * p.lda + src * 8, &lA[0][flat * 8]);
    }
#pragma unroll
    for (int it = 0; it < 4; ++it) {
        int flat = it * 256 + t, row = flat >> 3, src = (flat & 7) ^ (row & 7);
        gload_lds16(Bb + (long)row * p.ldb + src * 8, &lB[0][flat * 8]);
    }
    __syncthreads();

    for (int kt = 0; kt < nk; ++kt) {
        const int cur = kt & 1, nxt = cur ^ 1;
        if (kt + 1 < nk) {
            const long kb = (long)(kt + 1) * 64;
#pragma unroll
            for (int it = 0; it < AITS; ++it) {
                int flat = it * 256 + t, row = flat >> 3, src = (flat & 7) ^ (row & 7);
                gload_lds16(Ab + (long)row * p.lda + kb + src * 8, &lA[nxt][flat * 8]);
            }
#pragma unroll
            for (int it = 0; it < 4; ++it) {
                int flat = it * 256 + t, row = flat >> 3, src = (flat & 7) ^ (row & 7);
                gload_lds16(Bb + (long)row * p.ldb + kb + src * 8, &lB[nxt][flat * 8]);
            }
        }
#pragma unroll
        for (int kk = 0; kk < 2; ++kk) {
            const int q = kk * 4 + quad;
            short8 aF[MW], bF[4];
#pragma unroll
            for (int mi = 0; mi < MW; mi++) {
                int row = wm + mi * 16 + fr;
                aF[mi] = *(const short8*)&lA[cur][row * 64 + (q ^ (row & 7)) * 8];
            }
#pragma unroll
            for (int ni = 0; ni < 4; ni++) {
                int row = wn + ni * 16 + fr;
                bF[ni] = *(const short8*)&lB[cur][row * 64 + (q ^ (row & 7)) * 8];
            }
#pragma unroll
            for (int mi = 0; mi < MW; mi++)
#pragma unroll
                for (int ni = 0; ni < 4; ni++)
                    acc[mi][ni] = __builtin_amdgcn_mfma_f32_16x16x32_bf16(
                        aF[mi], bF[ni], acc[mi][ni], 0, 0, 0);
        }
        __syncthreads();
    }

    // EPI3: hoist per-row sigmoid (was recomputed per column)
    float sgv[MW][4];
    if (EPI == 3) {
#pragma unroll
        for (int mi = 0; mi < MW; mi++)
#pragma unroll
            for (int r = 0; r < 4; r++) {
                long row = m0 + wm + mi * 16 + quad * 4 + r;
                sgv[mi][r] = fsig(p.gate_pre[row * 8 + z] + bf2f(p.bgate[z]));
            }
    }

    // Epilogue: D row = quad*4+reg, col = lane&15
#pragma unroll
    for (int mi = 0; mi < MW; mi++) {
#pragma unroll
        for (int ni = 0; ni < 4; ni++) {
            const int mg = m0 + wm + mi * 16 + quad * 4;
            const int ng = n0 + wn + ni * 16 + fr;
#pragma unroll
            for (int r = 0; r < 4; r++) {
                float v = acc[mi][ni][r];
                const long row = mg + r;
                if (EPI == 1) {        // tanh(acc+add+bias) -> bf16   [link->fhs]
                    float ad = bf2f(p.add[z * p.addOff + row * p.ldadd + ng]);
                    v = ftanh(v + ad + bf2f(p.bias[p.biasOff[z] + ng]));
                    ((u16*)p.C)[p.cOff[z] + row * p.ldc + ng] = f2bf(v);
                } else if (EPI == 3) { // sig(gate)*tanh(acc+bias)     [upd]
                    v = ftanh(v + bf2f(p.bias[p.biasOff[z] + ng])) * sgv[mi][r];
                    ((u16*)p.C)[p.cOff[z] + row * p.ldc + ng] = f2bf(v);
                } else if (EPI == 4) { // encode mix: h_b, summ_b, h(f32)
                    v = ftanh(v + bf2f(p.bias[ng]));
                    u16 b = f2bf(v);
                    ((u16*)p.C)[row * 512 + ng] = b;
                    p.C3[row * 512 + ng] = b;
                    p.C2[row * 512 + ng] = v;
                } else if (EPI == 6) { // (acc+bias) -> bf16            [cin]
                    v = v + bf2f(p.bias[p.biasOff[z] + ng]);
                    ((u16*)p.C)[p.cOff[z] + row * p.ldc + ng] = f2bf(v);
                } else {               // EPI 7: tanh(acc+add) -> bf16  [f0]
                    float ad = bf2f(p.add[row * p.ldadd + ng]);
                    v = ftanh(v + ad);
                    ((u16*)p.C)[row * p.ldc + ng] = f2bf(v);
                }
            }
        }
    }
}

// ---------------------------------------------------------------------------
// Fused GRU-GEMM: per block (64 b-rows, s, 128 w-cols) accumulate r,z,inn,hn
// via K=1024 concat A=[feats;hs_b] x Wcat=[W_ih|W_hh], then GRU + prismion +
// gate-partial in the epilogue. BK=32, double-buffered, 56 KB LDS.
// Swizzle f(row)=(row>>1)&3: 16 consecutive rows cycle all (parity,chunk)
// bank groups -> 2-way only (free). (row&3 left a 4-way pattern - R8 2.6M.)
// ---------------------------------------------------------------------------
struct GGP {
    const u16* fhs_in;    // [b][s][1024]  (feats | hs_b)
    u16* fhs_out;         // write hs_b' at [b][s][512+w]
    const u16* Wcat;      // [s][1536][1024]
    const u16* b_ih;      // [s][1536]
    const u16* b_hh;      // [s][1536]
    u16* prism;           // [b][s][512]
    float* gate_pre;      // [b][8]  (atomicAdd, pre-zeroed)
    const u16* Wg;        // [s][512]
    const u16* phase;     // [s][512]
    const u16* pgain;     // [s][512]
};

__global__ __launch_bounds__(256, 2) void grug_k(GGP p) {
    __shared__ __align__(16) u16 sA[2][64 * 32];        //  8 KB
    __shared__ __align__(16) u16 sW[2][3][128 * 32];    // 48 KB
    const int t    = threadIdx.x;
    const int lane = t & 63;
    const int wv   = t >> 6;
    const int s    = blockIdx.x >> 2;
    const int w0   = (blockIdx.x & 3) * 128;
    const int m0   = blockIdx.y * 64;
    const int fr   = lane & 15;
    const int quad = lane >> 4;
    const int wn   = wv * 32;          // wave's n-range (32 cols)

    const u16* Ab = p.fhs_in + (long)m0 * 8192 + s * 1024;
    const u16* Wb = p.Wcat + (long)s * 1536 * 1024;

    f32x4 acc[4][4][2];   // [q: r,z,inn,hn][mi 0..3][ni 0..1]
#pragma unroll
    for (int q = 0; q < 4; q++)
#pragma unroll
        for (int mi = 0; mi < 4; mi++)
#pragma unroll
            for (int ni = 0; ni < 2; ni++) acc[q][mi][ni] = (f32x4){0.f,0.f,0.f,0.f};

    const int arow = t >> 2, ac4 = t & 3, asrc = ac4 ^ ((arow >> 1) & 3);

    auto stageA = [&](int buf, long kb) {
        gload_lds16(Ab + (long)arow * 8192 + kb + asrc * 8, &sA[buf][t * 8]);
    };
    auto stageW = [&](int buf, long kb) {
#pragma unroll
        for (int q = 0; q < 3; q++)
#pragma unroll
            for (int it = 0; it < 2; ++it) {
                int flat = it * 256 + t, row = flat >> 2, src = (flat & 3) ^ ((row >> 1) & 3);
                long g = (long)(q * 512 + w0 + row);
                gload_lds16(Wb + g * 1024 + kb + src * 8, &sW[buf][q][flat * 8]);
            }
    };

    stageA(0, 0); stageW(0, 0);
    __syncthreads();

    for (int kt = 0; kt < 32; ++kt) {
        const int cur = kt & 1, nxt = cur ^ 1;
        if (kt + 1 < 32) { stageA(nxt, (long)(kt + 1) * 32); stageW(nxt, (long)(kt + 1) * 32); }
        const int qsel = (kt < 16) ? 2 : 3;   // inn (k<512) vs hn (k>=512)
        short8 aF[4], bF[3][2];
#pragma unroll
        for (int mi = 0; mi < 4; mi++) {
            int row = mi * 16 + fr;
            aF[mi] = *(const short8*)&sA[cur][row * 32 + ((quad ^ ((row >> 1) & 3)) & 3) * 8];
        }
#pragma unroll
        for (int q = 0; q < 3; q++)
#pragma unroll
            for (int ni = 0; ni < 2; ni++) {
                int row = wn + ni * 16 + fr;
                bF[q][ni] = *(const short8*)&sW[cur][q][row * 32 + ((quad ^ ((row >> 1) & 3)) & 3) * 8];
            }
#pragma unroll
        for (int mi = 0; mi < 4; mi++)
#pragma unroll
            for (int ni = 0; ni < 2; ni++) {
                acc[0][mi][ni] = __builtin_amdgcn_mfma_f32_16x16x32_bf16(aF[mi], bF[0][ni], acc[0][mi][ni], 0, 0, 0);
                acc[1][mi][ni] = __builtin_amdgcn_mfma_f32_16x16x32_bf16(aF[mi], bF[1][ni], acc[1][mi][ni], 0, 0, 0);
                if (qsel == 2)
                    acc[2][mi][ni] = __builtin_amdgcn_mfma_f32_16x16x32_bf16(aF[mi], bF[2][ni], acc[2][mi][ni], 0, 0, 0);
                else
                    acc[3][mi][ni] = __builtin_amdgcn_mfma_f32_16x16x32_bf16(aF[mi], bF[2][ni], acc[3][mi][ni], 0, 0, 0);
            }
        __syncthreads();
    }

    // Epilogue: ni-outer so the 9 per-column params load once per column.
    const u16* bih = p.b_ih + (long)s * 1536;
    const u16* bhh = p.b_hh + (long)s * 1536;
    float gp[4][4];
#pragma unroll
    for (int mi = 0; mi < 4; mi++)
#pragma unroll
        for (int r = 0; r < 4; r++) gp[mi][r] = 0.f;

#pragma unroll
    for (int ni = 0; ni < 2; ni++) {
        const int col = w0 + wn + ni * 16 + fr;          // w in [0,512)
        const float br  = bf2f(bih[col])        + bf2f(bhh[col]);
        const float bz  = bf2f(bih[512 + col])  + bf2f(bhh[512 + col]);
        const float bin = bf2f(bih[1024 + col]);
        const float bhn = bf2f(bhh[1024 + col]);
        const float ph  = bf2f(p.phase[s * 512 + col]);
        const float gain = fsoftplus(bf2f(p.pgain[s * 512 + col]));
        const float wg  = bf2f(p.Wg[s * 512 + col]);
#pragma unroll
        for (int mi = 0; mi < 4; mi++) {
#pragma unroll
            for (int r = 0; r < 4; r++) {
                const long b = m0 + mi * 16 + quad * 4 + r;
                float rv = fsig(acc[0][mi][ni][r] + br);
                float zv = fsig(acc[1][mi][ni][r] + bz);
                float nv = ftanh(acc[2][mi][ni][r] + bin + rv * (acc[3][mi][ni][r] + bhn));
                float hold = bf2f(p.fhs_in[b * 8192 + s * 1024 + 512 + col]);
                float hv = (1.f - zv) * nv + zv * hold;
                p.fhs_out[b * 8192 + s * 1024 + 512 + col] = f2bf(hv);
                float c = __cosf(hv + ph);
                p.prism[b * 4096 + s * 512 + col] = f2bf(c * c * gain);
                gp[mi][r] += wg * hv;
            }
        }
    }
    // reduce over fr (16 lanes within quad), then one atomic per row
#pragma unroll
    for (int m = 1; m < 16; m <<= 1)
#pragma unroll
        for (int mi = 0; mi < 4; mi++)
#pragma unroll
            for (int r = 0; r < 4; r++) gp[mi][r] += __shfl_xor(gp[mi][r], m, 64);
    if (fr == 0) {
#pragma unroll
        for (int mi = 0; mi < 4; mi++)
#pragma unroll
            for (int r = 0; r < 4; r++) {
                long b = m0 + mi * 16 + quad * 4 + r;
                atomicAdd(&p.gate_pre[b * 8 + s], gp[mi][r]);
            }
    }
}

// ---------------------------------------------------------------------------
// Encode: masked mean / masked max / last token -> cat [B,1536]
// ---------------------------------------------------------------------------
__global__ __launch_bounds__(256) void encode_k(const int* __restrict__ x,
                                                const u16* __restrict__ embed,
                                                u16* __restrict__ cat) {
    __shared__ int toks[128];
    __shared__ int cnt_s;
    const int b = blockIdx.x, t = threadIdx.x;
    if (t < 128) toks[t] = x[b * 128 + t];
    __syncthreads();
    if (t == 0) {
        int c = 0;
        for (int l = 0; l < 128; l++) c += (toks[l] != 0);
        cnt_s = c;
    }
    __syncthreads();
    const int cnt = cnt_s;
    const int lastTok = toks[cnt > 0 ? cnt - 1 : 0];
    for (int w = t; w < 512; w += 256) {
        float sum = 0.f, mx = -10000.f;
        for (int l = 0; l < 128; l++) {
            int tok = toks[l];
            if (tok != 0) {
                float e = bf2f(embed[tok * 512 + w]);
                sum += e;
                mx = fmaxf(mx, e);
            }
        }
        float mean = sum / (float)(cnt > 0 ? cnt : 1);
        float last = bf2f(embed[lastTok * 512 + w]);
        cat[(long)b * 1536 + w]        = f2bf(mean);
        cat[(long)b * 1536 + 512 + w]  = f2bf(mx);
        cat[(long)b * 1536 + 1024 + w] = f2bf(last);
    }
}

// ---------------------------------------------------------------------------
// delta = sum_s upd / sqrt(S);  h = tanh(h*decay + delta); h_b = bf16(h)
// ---------------------------------------------------------------------------
__global__ __launch_bounds__(256) void hupd_k(const u16* __restrict__ upd,
                                              float* __restrict__ h,
                                              u16* __restrict__ h_b,
                                              const u16* __restrict__ decay_p) {
    const int idx = blockIdx.x * 256 + threadIdx.x;
    const int b = idx >> 9, w = idx & 511;
    const long base = (long)b * 4096 + w;
    float dsum = 0.f;
#pragma unroll
    for (int s = 0; s < 8; s++) dsum += bf2f(upd[base + s * 512]);
    const float decay = fsig(bf2f(decay_p[0]));
    const float hv = ftanh(h[idx] * decay + dsum * 0.35355339059327373f);
    h[idx] = hv;
    h_b[idx] = f2bf(hv);
}

// ---------------------------------------------------------------------------
// Final head; output dtype follows detected input dtype.
// ---------------------------------------------------------------------------
__global__ __launch_bounds__(64) void out_k(const float* __restrict__ h,
                                            const u16* __restrict__ Wout,
                                            const u16* __restrict__ bout,
                                            void* __restrict__ out,
                                            const int* __restrict__ flag) {
    const int b = blockIdx.x, lane = threadIdx.x;
    const int isbf = *flag;
    for (int j = 0; j < 10; j++) {
        float p = 0.f;
#pragma unroll
        for (int k = 0; k < 8; k++) {
            int w = lane + k * 64;
            p += h[(long)b * 512 + w] * bf2f(Wout[j * 512 + w]);
        }
#pragma unroll
        for (int off = 32; off; off >>= 1) p += __shfl_down(p, off, 64);
        if (lane == 0) {
            float val = p + bf2f(bout[j]);
            if (isbf) ((u16*)out)[b * 10 + j] = f2bf(val);
            else      ((float*)out)[b * 10 + j] = val;
        }
    }
}

// ---------------------------------------------------------------------------
extern "C" void kernel_launch(void* const* d_in, const int* in_sizes, int n_in,
                              void* d_out, int out_size, void* d_ws, size_t ws_size,
                              hipStream_t stream) {
    (void)n_in; (void)out_size; (void)ws_size;
    const int* x = (const int*)d_in[0];

    char* pp = (char*)d_ws;
    auto carve = [&](size_t n) { char* r = pp; pp += (n + 255) & ~(size_t)255; return (void*)r; };

    // canonical bf16 parameter block (~44 MB)
    CT ct;
    size_t ctot = 0;
    for (int i = 0; i < 20; i++) {
        ct.src[i] = d_in[i + 1];
        ct.n[i]   = in_sizes[i + 1];
        ct.off[i] = (int)ctot;
        ctot += ((size_t)in_sizes[i + 1] + 15) & ~(size_t)15;
    }
    u16* canon = (u16*)carve(ctot * 2);
    const u16* embed  = canon + ct.off[0];
    const u16* W_mix  = canon + ct.off[1];
    const u16* b_mix  = canon + ct.off[2];
    const u16* W_in   = canon + ct.off[3];
    const u16* b_in   = canon + ct.off[4];
    const u16* W_link = canon + ct.off[5];
    const u16* b_link = canon + ct.off[6];
    const u16* W_ih   = canon + ct.off[7];
    const u16* b_ih   = canon + ct.off[8];
    const u16* W_hh   = canon + ct.off[9];
    const u16* b_hh   = canon + ct.off[10];
    const u16* W_gate = canon + ct.off[11];
    const u16* b_gate = canon + ct.off[12];
    const u16* phase  = canon + ct.off[13];
    const u16* pgain  = canon + ct.off[14];
    const u16* W_delta= canon + ct.off[15];
    const u16* b_delta= canon + ct.off[16];
    const u16* decayp = canon + ct.off[17];
    const u16* W_out  = canon + ct.off[18];
    const u16* b_out  = canon + ct.off[19];

    int*   flag   = (int*)  carve(256);
    u16*   Wcat   = (u16*)  carve((size_t)8 * 1536 * 1024 * 2);  // 25 MB
    u16*   cat    = (u16*)  carve((size_t)1024 * 1536 * 2);
    u16*   h_b    = (u16*)  carve((size_t)1024 * 512 * 2);
    u16*   summ_b = (u16*)  carve((size_t)1024 * 512 * 2);
    float* h      = (float*)carve((size_t)1024 * 512 * 4);
    u16*   cin    = (u16*)  carve((size_t)1024 * 4096 * 2);
    u16*   f0     = (u16*)  carve((size_t)1024 * 4096 * 2);
    u16*   fhs0   = (u16*)  carve((size_t)1024 * 8192 * 2);      // 16 MB
    u16*   fhs1   = (u16*)  carve((size_t)1024 * 8192 * 2);      // 16 MB
    u16*   prism  = (u16*)  carve((size_t)1024 * 4096 * 2);
    u16*   upd    = (u16*)  carve((size_t)1024 * 4096 * 2);
    float* gate_pre = (float*)carve((size_t)1024 * 8 * 4);

    (void)hipMemsetAsync(fhs0, 0, (size_t)1024 * 8192 * 2, stream);
    (void)hipMemsetAsync(fhs1, 0, (size_t)1024 * 8192 * 2, stream);

    detect_k<<<dim3(1), dim3(256), 0, stream>>>((const u16*)d_in[1], flag);
    conv_k<<<dim3(1024), dim3(256), 0, stream>>>(ct, canon, flag);
    pack_k<<<dim3(3072), dim3(256), 0, stream>>>(W_ih, W_hh, Wcat);
    encode_k<<<dim3(1024), dim3(256), 0, stream>>>(x, embed, cat);

    {   // summary = tanh(cat @ W_mix^T + b_mix) -> h_b, summ_b, h
        GP p{}; p.A = cat; p.lda = 1536; p.Bw = W_mix; p.ldb = 1536;
        p.bias = b_mix; p.C = h_b; p.ldc = 512; p.C2 = h; p.C3 = summ_b;
        p.K = 1536; p.nt = 4;
        gemm_k<4, 64><<<dim3(4, 16, 1), dim3(256), 0, stream>>>(p);
    }
    {   // cin = summary @ W_in[:, :, 512:]^T + b_in
        GP p{}; p.A = summ_b; p.lda = 512; p.Bw = W_in + 512; p.ldb = 1024;
        p.bias = b_in; p.C = cin; p.ldc = 4096; p.K = 512; p.nt = 32;
        gemm_k<6, 64><<<dim3(32, 16, 1), dim3(256), 0, stream>>>(p);
    }

    for (int step = 0; step < 12; ++step) {
        u16* fhs_cur = (step & 1) ? fhs1 : fhs0;
        u16* fhs_nxt = (step & 1) ? fhs0 : fhs1;
        {   // f0 = tanh(h @ W_in[:, :, :512]^T + cin)
            GP p{}; p.A = h_b; p.lda = 512; p.Bw = W_in; p.ldb = 1024;
            p.add = cin; p.ldadd = 4096; p.C = f0; p.ldc = 4096;
            p.K = 512; p.nt = 32;
            gemm_k<7, 64><<<dim3(32, 16, 1), dim3(256), 0, stream>>>(p);
        }
        {   // feats = tanh(f0 + prev @ W_link^T + b_link) -> fhs_cur[:, s, 0:512]
            GP p{}; p.A = f0; p.lda = 4096;
            for (int s = 0; s < 8; s++) p.aOff[s] = (long)((s + 7) & 7) * 512;
            p.Bw = W_link; p.ldb = 512;
            for (int s = 0; s < 8; s++) p.bwOff[s] = (long)s * 512 * 512;
            p.bias = b_link;
            for (int s = 0; s < 8; s++) p.biasOff[s] = (long)s * 512;
            p.add = f0; p.ldadd = 4096; p.addOff = 512;
            p.C = fhs_cur; p.ldc = 8192;
            for (int s = 0; s < 8; s++) p.cOff[s] = (long)s * 1024;
            p.K = 512; p.nt = 4;
            gemm_k<1, 64><<<dim3(32, 16, 1), dim3(256), 0, stream>>>(p);
        }
        (void)hipMemsetAsync(gate_pre, 0, (size_t)1024 * 8 * 4, stream);
        {   // fused GRU-GEMM
            GGP g{};
            g.fhs_in = fhs_cur; g.fhs_out = fhs_nxt; g.Wcat = Wcat;
            g.b_ih = b_ih; g.b_hh = b_hh; g.prism = prism; g.gate_pre = gate_pre;
            g.Wg = W_gate; g.phase = phase; g.pgain = pgain;
            grug_k<<<dim3(32, 16, 1), dim3(256), 0, stream>>>(g);
        }
        {   // upd = sig(gate)*tanh(prism @ W_delta^T + b_delta) -> bf16
            GP p{}; p.A = prism; p.lda = 4096;
            for (int s = 0; s < 8; s++) p.aOff[s] = (long)s * 512;
            p.Bw = W_delta; p.ldb = 512;
            for (int s = 0; s < 8; s++) p.bwOff[s] = (long)s * 512 * 512;
            p.bias = b_delta;
            for (int s = 0; s < 8; s++) p.biasOff[s] = (long)s * 512;
            p.gate_pre = gate_pre; p.bgate = b_gate;
            p.C = upd; p.ldc = 4096;
            for (int s = 0; s < 8; s++) p.cOff[s] = (long)s * 512;
            p.K = 512; p.nt = 4;
            gemm_k<3, 64><<<dim3(32, 16, 1), dim3(256), 0, stream>>>(p);
        }
        hupd_k<<<dim3(2048), dim3(256), 0, stream>>>(upd, h, h_b, decayp);
    }

    out_k<<<dim3(1024), dim3(64), 0, stream>>>(h, W_out, b_out, d_out, flag);
}